// Round 1
// baseline (2522.155 us; speedup 1.0000x reference)
//
#include <hip/hip_runtime.h>
#include <hip/hip_bf16.h>

#define S_ 1024
#define H_ 2048
#define NH_ 16
#define NKV_ 4
#define HD_ 128
#define E_ 8
#define F_ 256
#define EPS_ 1e-6f
#define SCALE_ 0.08838834764831845f  // 128^-0.5

static __device__ __forceinline__ unsigned short f2bf(float x) {
  unsigned u = __float_as_uint(x);
  unsigned r = (u + 0x7FFFu + ((u >> 16) & 1u)) >> 16;
  return (unsigned short)r;
}
static __device__ __forceinline__ float bf2f(unsigned short b) {
  return __uint_as_float(((unsigned)b) << 16);
}

// ---------------- RMSNorm #1 ----------------
__global__ void rmsnorm1_kernel(const float* __restrict__ in, const float* __restrict__ w,
                                float* __restrict__ out) {
  int s = blockIdx.x, tid = threadIdx.x;
  const float* row = in + s * H_;
  __shared__ float red[256];
  float ss = 0.f;
  for (int i = tid; i < H_; i += 256) { float v = row[i]; ss += v * v; }
  red[tid] = ss; __syncthreads();
  for (int off = 128; off > 0; off >>= 1) {
    if (tid < off) red[tid] += red[tid + off];
    __syncthreads();
  }
  float rs = rsqrtf(red[0] / H_ + EPS_);
  for (int i = tid; i < H_; i += 256) out[s * H_ + i] = row[i] * rs * w[i];
}

// ---------------- generic fp32 GEMM: C[M,N] = A[M,K] @ B[N,K]^T (+resid) ------
__global__ __launch_bounds__(256) void gemm_rt_kernel(const float* __restrict__ A,
                                                      const float* __restrict__ B,
                                                      float* __restrict__ C,
                                                      const float* __restrict__ resid,
                                                      int M, int N, int K) {
  __shared__ float As[16][68];
  __shared__ float Bs[16][68];
  int bm = blockIdx.y * 64, bn = blockIdx.x * 64;
  int tid = threadIdx.x;
  int tx = tid & 15, ty = tid >> 4;
  int lm = tid >> 4, lk = tid & 15;
  float acc[4][4];
#pragma unroll
  for (int i = 0; i < 4; ++i)
#pragma unroll
    for (int j = 0; j < 4; ++j) acc[i][j] = 0.f;
  for (int k0 = 0; k0 < K; k0 += 16) {
#pragma unroll
    for (int i = 0; i < 4; ++i) {
      int m = lm + 16 * i;
      As[lk][m] = A[(size_t)(bm + m) * K + k0 + lk];
      Bs[lk][m] = B[(size_t)(bn + m) * K + k0 + lk];
    }
    __syncthreads();
#pragma unroll
    for (int kk = 0; kk < 16; ++kk) {
      float4 a4 = *(const float4*)&As[kk][ty * 4];
      float4 b4 = *(const float4*)&Bs[kk][tx * 4];
      float av[4] = {a4.x, a4.y, a4.z, a4.w};
      float bv[4] = {b4.x, b4.y, b4.z, b4.w};
#pragma unroll
      for (int i = 0; i < 4; ++i)
#pragma unroll
        for (int j = 0; j < 4; ++j) acc[i][j] += av[i] * bv[j];
    }
    __syncthreads();
  }
#pragma unroll
  for (int i = 0; i < 4; ++i) {
    int m = bm + ty * 4 + i;
#pragma unroll
    for (int j = 0; j < 4; ++j) {
      int nn = bn + tx * 4 + j;
      float v = acc[i][j];
      if (resid) v += resid[(size_t)m * N + nn];
      C[(size_t)m * N + nn] = v;
    }
  }
}

// ---------------- RoPE (in place on q and k) ----------------
__global__ void rope_kernel(float* __restrict__ qb, float* __restrict__ kb,
                            const float* __restrict__ cosb, const float* __restrict__ sinb) {
  int s = blockIdx.x, tid = threadIdx.x;
  for (int idx = tid; idx < (NH_ + NKV_) * 64; idx += 256) {
    int hh = idx >> 6;
    int d = idx & 63;
    float c0 = cosb[s * HD_ + d], s0 = sinb[s * HD_ + d];
    float c1 = cosb[s * HD_ + d + 64], s1 = sinb[s * HD_ + d + 64];
    float* p;
    if (hh < NH_) p = qb + (size_t)s * 2048 + hh * 128;
    else          p = kb + (size_t)s * 512 + (hh - NH_) * 128;
    float a = p[d], b = p[d + 64];
    p[d] = a * c0 - b * s0;
    p[d + 64] = b * c1 + a * s1;
  }
}

// ---------------- flash attention (causal GQA) ----------------
__global__ __launch_bounds__(64, 1) void attn_kernel(const float* __restrict__ qb,
                                                     const float* __restrict__ kb,
                                                     const float* __restrict__ vb,
                                                     float* __restrict__ ob) {
  int n = blockIdx.x, qt = blockIdx.y;
  int g = n >> 2;
  int tid = threadIdx.x;  // 64
  int qrow = qt * 64 + tid;
  __shared__ unsigned short qls[64][130];
  __shared__ unsigned short kT[128][36];  // [d][j] transposed, bf16
  __shared__ float vls[32][128];
  // stage q tile (64 rows x 128) as bf16
  for (int idx = tid; idx < 64 * 32; idx += 64) {
    int r = idx >> 5, d4 = (idx & 31) * 4;
    float4 qv = *(const float4*)&qb[(size_t)(qt * 64 + r) * 2048 + n * 128 + d4];
    qls[r][d4] = f2bf(qv.x); qls[r][d4 + 1] = f2bf(qv.y);
    qls[r][d4 + 2] = f2bf(qv.z); qls[r][d4 + 3] = f2bf(qv.w);
  }
  float acc[128];
#pragma unroll
  for (int d = 0; d < 128; ++d) acc[d] = 0.f;
  float m = -1e30f, l = 0.f;
  int nt = qt * 2 + 2;  // k-subtiles of 32 up to (qt+1)*64
  for (int t = 0; t < nt; ++t) {
    int k0 = t * 32;
    __syncthreads();
    for (int idx = tid; idx < 32 * 32; idx += 64) {
      int j = idx >> 5, d4 = (idx & 31) * 4;
      size_t base = (size_t)(k0 + j) * 512 + g * 128 + d4;
      float4 kv = *(const float4*)&kb[base];
      kT[d4][j] = f2bf(kv.x); kT[d4 + 1][j] = f2bf(kv.y);
      kT[d4 + 2][j] = f2bf(kv.z); kT[d4 + 3][j] = f2bf(kv.w);
      *(float4*)&vls[j][d4] = *(const float4*)&vb[base];
    }
    __syncthreads();
    if (k0 <= qrow) {
      float sc[32];
#pragma unroll
      for (int j = 0; j < 32; ++j) sc[j] = 0.f;
      for (int d = 0; d < 128; ++d) {
        float qd = bf2f(qls[tid][d]);
        const unsigned* kt2 = (const unsigned*)&kT[d][0];
#pragma unroll
        for (int j2 = 0; j2 < 16; ++j2) {
          unsigned u = kt2[j2];
          float klo = __uint_as_float(u << 16);
          float khi = __uint_as_float(u & 0xffff0000u);
          sc[2 * j2] += qd * klo;
          sc[2 * j2 + 1] += qd * khi;
        }
      }
      float mnew = m;
#pragma unroll
      for (int j = 0; j < 32; ++j) {
        sc[j] = (k0 + j <= qrow) ? sc[j] * SCALE_ : -1e30f;
        mnew = fmaxf(mnew, sc[j]);
      }
      float corr = __expf(m - mnew);
      float p[32];
      float psum = 0.f;
#pragma unroll
      for (int j = 0; j < 32; ++j) { p[j] = __expf(sc[j] - mnew); psum += p[j]; }
      l = l * corr + psum;
#pragma unroll
      for (int d = 0; d < 128; ++d) acc[d] *= corr;
      for (int j = 0; j < 32; ++j) {
        float pj = p[j];
        const float4* v4 = (const float4*)&vls[j][0];
#pragma unroll
        for (int d4 = 0; d4 < 32; ++d4) {
          float4 vv = v4[d4];
          acc[4 * d4] += pj * vv.x;
          acc[4 * d4 + 1] += pj * vv.y;
          acc[4 * d4 + 2] += pj * vv.z;
          acc[4 * d4 + 3] += pj * vv.w;
        }
      }
      m = mnew;
    }
  }
  float inv = 1.f / l;
#pragma unroll
  for (int d4 = 0; d4 < 32; ++d4) {
    float4 o;
    o.x = acc[4 * d4] * inv; o.y = acc[4 * d4 + 1] * inv;
    o.z = acc[4 * d4 + 2] * inv; o.w = acc[4 * d4 + 3] * inv;
    *(float4*)&ob[(size_t)qrow * 2048 + n * 128 + d4 * 4] = o;
  }
}

// ---------------- RMSNorm #2 (row norm then per-head norm) ----------------
__global__ void rmsnorm2_kernel(const float* __restrict__ hin, const float* __restrict__ ln2w,
                                const float* __restrict__ mhw, float* __restrict__ yout) {
  int s = blockIdx.x, tid = threadIdx.x;  // 256
  const float* row = hin + (size_t)s * H_;
  __shared__ float y1[H_];
  __shared__ float red[256];
  __shared__ float ph[16][17];
  float ss = 0.f;
  for (int i = tid; i < H_; i += 256) { float v = row[i]; ss += v * v; }
  red[tid] = ss; __syncthreads();
  for (int off = 128; off > 0; off >>= 1) {
    if (tid < off) red[tid] += red[tid + off];
    __syncthreads();
  }
  float rs1 = rsqrtf(red[0] / H_ + EPS_);
  for (int i = tid; i < H_; i += 256) y1[i] = row[i] * rs1 * ln2w[i];
  __syncthreads();
  int n = tid >> 4, j = tid & 15;
  float s2 = 0.f;
  for (int d = j * 8; d < j * 8 + 8; ++d) { float v = y1[n * 128 + d]; s2 += v * v; }
  ph[n][j] = s2; __syncthreads();
  if (j == 0) {
    float t = 0.f;
    for (int q = 0; q < 16; ++q) t += ph[n][q];
    ph[n][16] = rsqrtf(t / HD_ + EPS_);
  }
  __syncthreads();
  for (int i = tid; i < H_; i += 256) {
    int hn = i >> 7;
    yout[(size_t)s * H_ + i] = y1[i] * ph[hn][16] * mhw[i];
  }
}

// ---------------- router: softmax + top2 + scatter into expert lists ---------
__global__ void route_kernel(const float* __restrict__ yb, const float* __restrict__ rw,
                             int* __restrict__ cnt, int* __restrict__ idxb,
                             float* __restrict__ wtb) {
  int s = blockIdx.x, tid = threadIdx.x;  // 128
  int n = tid >> 3, e = tid & 7;
  const float* yrow = yb + (size_t)s * 2048 + n * 128;
  const float* wrow = rw + (size_t)(n * 8 + e) * 128;
  float lg = 0.f;
  for (int d = 0; d < 128; ++d) lg += yrow[d] * wrow[d];
  float mx = lg;
  for (int off = 1; off < 8; off <<= 1) mx = fmaxf(mx, __shfl_xor(mx, off));
  float p = __expf(lg - mx);
  float sum = p;
  for (int off = 1; off < 8; off <<= 1) sum += __shfl_xor(sum, off);
  float rp = p / sum;
  float v1 = rp; int i1 = e;
  for (int off = 1; off < 8; off <<= 1) {
    float ov = __shfl_xor(v1, off); int oi = __shfl_xor(i1, off);
    if (ov > v1 || (ov == v1 && oi < i1)) { v1 = ov; i1 = oi; }
  }
  float v2 = (e == i1) ? -1e30f : rp; int i2 = e;
  for (int off = 1; off < 8; off <<= 1) {
    float ov = __shfl_xor(v2, off); int oi = __shfl_xor(i2, off);
    if (ov > v2 || (ov == v2 && oi < i2)) { v2 = ov; i2 = oi; }
  }
  if (e == 0) {
    float wsum = v1 + v2;
    int pe1 = n * 8 + i1;
    int pos1 = atomicAdd(&cnt[pe1], 1);
    idxb[pe1 * S_ + pos1] = s; wtb[pe1 * S_ + pos1] = v1 / wsum;
    int pe2 = n * 8 + i2;
    int pos2 = atomicAdd(&cnt[pe2], 1);
    idxb[pe2 * S_ + pos2] = s; wtb[pe2 * S_ + pos2] = v2 / wsum;
  }
}

// ---------------- gathered top-2 expert FFN, accumulate into out -------------
__global__ void ffn_kernel(const float* __restrict__ yb,
                           const float* __restrict__ kw, const float* __restrict__ uw,
                           const float* __restrict__ vw,
                           const int* __restrict__ cnt, const int* __restrict__ idxb,
                           const float* __restrict__ wtb, float* __restrict__ out) {
  int pe = blockIdx.x;  // n*8+e
  int n = pe >> 3, e = pe & 7, g = n >> 2;
  int tid = threadIdx.x;  // 256
  int c = cnt[pe];
  const float* KW = kw + (size_t)((g * 8 + e) * 256) * 128;
  const float* UW = uw + (size_t)((g * 8 + e) * 256) * 128;
  const float* VW = vw + (size_t)((g * 8 + e) * 256) * 128;
  __shared__ float yls[8][128];
  __shared__ float acls[8][256];
  __shared__ int sidx[8];
  __shared__ float swt[8];
  for (int base = blockIdx.y * 8; base < c; base += gridDim.y * 8) {
    int nr = min(8, c - base);
    if (tid < 8) {
      sidx[tid] = (tid < nr) ? idxb[pe * S_ + base + tid] : 0;
      swt[tid] = (tid < nr) ? wtb[pe * S_ + base + tid] : 0.f;
    }
    __syncthreads();
    for (int idx = tid; idx < nr * 128; idx += 256) {
      int r = idx >> 7, d = idx & 127;
      yls[r][d] = yb[(size_t)sidx[r] * 2048 + n * 128 + d];
    }
    __syncthreads();
    {  // phase A: gate/up per f = tid
      int f = tid;
      float ga[8], ua[8];
#pragma unroll
      for (int r = 0; r < 8; ++r) { ga[r] = 0.f; ua[r] = 0.f; }
      const float* kr = KW + (size_t)f * 128;
      const float* ur = UW + (size_t)f * 128;
      for (int d = 0; d < 128; ++d) {
        float kv = kr[d], uv = ur[d];
#pragma unroll
        for (int r = 0; r < 8; ++r) { float yv = yls[r][d]; ga[r] += kv * yv; ua[r] += uv * yv; }
      }
#pragma unroll
      for (int r = 0; r < 8; ++r) {
        float gg = ga[r];
        float sig = 1.f / (1.f + __expf(-gg));
        acls[r][f] = gg * sig * ua[r] * swt[r];
      }
    }
    __syncthreads();
    {  // phase B: down proj, atomic accumulate
      int d = tid & 127, half = tid >> 7;
      float pa[8];
#pragma unroll
      for (int r = 0; r < 8; ++r) pa[r] = 0.f;
      const float* vr = VW + (size_t)half * 128 * 128;
      for (int f = 0; f < 128; ++f) {
        float vv = vr[(size_t)f * 128 + d];
#pragma unroll
        for (int r = 0; r < 8; ++r) pa[r] += acls[r][f + half * 128] * vv;
      }
      for (int r = 0; r < nr; ++r)
        atomicAdd(&out[(size_t)sidx[r] * 2048 + n * 128 + d], pa[r]);
    }
    __syncthreads();
  }
}

extern "C" void kernel_launch(void* const* d_in, const int* in_sizes, int n_in,
                              void* d_out, int out_size, void* d_ws, size_t ws_size,
                              hipStream_t stream) {
  const float* hidden = (const float*)d_in[0];
  const float* cosb   = (const float*)d_in[1];
  const float* sinb   = (const float*)d_in[2];
  // d_in[3] = attn_mask (unused; causal handled analytically)
  const float* ln1w   = (const float*)d_in[4];
  const float* ln2w   = (const float*)d_in[5];
  const float* wq     = (const float*)d_in[6];
  const float* wk     = (const float*)d_in[7];
  const float* wv     = (const float*)d_in[8];
  const float* wo     = (const float*)d_in[9];
  const float* mhw    = (const float*)d_in[10];
  const float* rw     = (const float*)d_in[11];
  const float* kww    = (const float*)d_in[12];
  const float* uww    = (const float*)d_in[13];
  const float* vww    = (const float*)d_in[14];
  float* out = (float*)d_out;

  float* ws = (float*)d_ws;
  float* x     = ws;                  // 2M
  float* qb    = x + 2097152;         // 2M
  float* kb    = qb + 2097152;        // 512K
  float* vb    = kb + 524288;         // 512K
  float* attnb = vb + 524288;         // 2M
  float* yb    = attnb + 2097152;     // 2M
  int*   cntb  = (int*)(yb + 2097152);       // 128
  int*   idxb  = cntb + 128;                 // 128K
  float* wtb   = (float*)(idxb + 131072);    // 128K

  hipMemsetAsync(cntb, 0, 128 * sizeof(int), stream);

  rmsnorm1_kernel<<<S_, 256, 0, stream>>>(hidden, ln1w, x);

  gemm_rt_kernel<<<dim3(2048 / 64, 1024 / 64), 256, 0, stream>>>(x, wq, qb, nullptr, 1024, 2048, 2048);
  gemm_rt_kernel<<<dim3(512 / 64, 1024 / 64), 256, 0, stream>>>(x, wk, kb, nullptr, 1024, 512, 2048);
  gemm_rt_kernel<<<dim3(512 / 64, 1024 / 64), 256, 0, stream>>>(x, wv, vb, nullptr, 1024, 512, 2048);

  rope_kernel<<<S_, 256, 0, stream>>>(qb, kb, cosb, sinb);

  attn_kernel<<<dim3(NH_, S_ / 64), 64, 0, stream>>>(qb, kb, vb, attnb);

  gemm_rt_kernel<<<dim3(2048 / 64, 1024 / 64), 256, 0, stream>>>(attnb, wo, out, hidden, 1024, 2048, 2048);

  rmsnorm2_kernel<<<S_, 256, 0, stream>>>(out, ln2w, mhw, yb);

  route_kernel<<<S_, 128, 0, stream>>>(yb, rw, cntb, idxb, wtb);

  ffn_kernel<<<dim3(NH_ * E_, 16), 256, 0, stream>>>(yb, kww, uww, vww, cntb, idxb, wtb, out);
}

// Round 3
// 1020.522 us; speedup vs baseline: 2.4714x; 2.4714x over previous
//
#include <hip/hip_runtime.h>
#include <hip/hip_bf16.h>

#define S_ 1024
#define H_ 2048
#define NH_ 16
#define NKV_ 4
#define HD_ 128
#define E_ 8
#define F_ 256
#define EPS_ 1e-6f
#define SCALE_ 0.08838834764831845f  // 128^-0.5

typedef __attribute__((ext_vector_type(8))) short bf16x8;
typedef __attribute__((ext_vector_type(4))) float f32x4;

static __device__ __forceinline__ unsigned short f2bf(float x) {
  unsigned u = __float_as_uint(x);
  unsigned r = (u + 0x7FFFu + ((u >> 16) & 1u)) >> 16;
  return (unsigned short)r;
}
static __device__ __forceinline__ float bf2f(unsigned short b) {
  return __uint_as_float(((unsigned)b) << 16);
}

// ---------------- RMSNorm #1 ----------------
__global__ void rmsnorm1_kernel(const float* __restrict__ in, const float* __restrict__ w,
                                float* __restrict__ out) {
  int s = blockIdx.x, tid = threadIdx.x;
  const float* row = in + s * H_;
  __shared__ float red[256];
  float ss = 0.f;
  for (int i = tid; i < H_; i += 256) { float v = row[i]; ss += v * v; }
  red[tid] = ss; __syncthreads();
  for (int off = 128; off > 0; off >>= 1) {
    if (tid < off) red[tid] += red[tid + off];
    __syncthreads();
  }
  float rs = rsqrtf(red[0] / H_ + EPS_);
  for (int i = tid; i < H_; i += 256) out[s * H_ + i] = row[i] * rs * w[i];
}

// ---------------- generic fp32 GEMM: C[M,N] = A[M,K] @ B[N,K]^T (+resid) ------
__global__ __launch_bounds__(256) void gemm_rt_kernel(const float* __restrict__ A,
                                                      const float* __restrict__ B,
                                                      float* __restrict__ C,
                                                      const float* __restrict__ resid,
                                                      int M, int N, int K) {
  __shared__ float As[16][68];
  __shared__ float Bs[16][68];
  int bm = blockIdx.y * 64, bn = blockIdx.x * 64;
  int tid = threadIdx.x;
  int tx = tid & 15, ty = tid >> 4;
  int lm = tid >> 4, lk = tid & 15;
  float acc[4][4];
#pragma unroll
  for (int i = 0; i < 4; ++i)
#pragma unroll
    for (int j = 0; j < 4; ++j) acc[i][j] = 0.f;
  for (int k0 = 0; k0 < K; k0 += 16) {
#pragma unroll
    for (int i = 0; i < 4; ++i) {
      int m = lm + 16 * i;
      As[lk][m] = A[(size_t)(bm + m) * K + k0 + lk];
      Bs[lk][m] = B[(size_t)(bn + m) * K + k0 + lk];
    }
    __syncthreads();
#pragma unroll
    for (int kk = 0; kk < 16; ++kk) {
      float4 a4 = *(const float4*)&As[kk][ty * 4];
      float4 b4 = *(const float4*)&Bs[kk][tx * 4];
      float av[4] = {a4.x, a4.y, a4.z, a4.w};
      float bv[4] = {b4.x, b4.y, b4.z, b4.w};
#pragma unroll
      for (int i = 0; i < 4; ++i)
#pragma unroll
        for (int j = 0; j < 4; ++j) acc[i][j] += av[i] * bv[j];
    }
    __syncthreads();
  }
#pragma unroll
  for (int i = 0; i < 4; ++i) {
    int m = bm + ty * 4 + i;
#pragma unroll
    for (int j = 0; j < 4; ++j) {
      int nn = bn + tx * 4 + j;
      float v = acc[i][j];
      if (resid) v += resid[(size_t)m * N + nn];
      C[(size_t)m * N + nn] = v;
    }
  }
}

// ---------------- RoPE (in place on q and k) ----------------
__global__ void rope_kernel(float* __restrict__ qb, float* __restrict__ kb,
                            const float* __restrict__ cosb, const float* __restrict__ sinb) {
  int s = blockIdx.x, tid = threadIdx.x;
  for (int idx = tid; idx < (NH_ + NKV_) * 64; idx += 256) {
    int hh = idx >> 6;
    int d = idx & 63;
    float c0 = cosb[s * HD_ + d], s0 = sinb[s * HD_ + d];
    float c1 = cosb[s * HD_ + d + 64], s1 = sinb[s * HD_ + d + 64];
    float* p;
    if (hh < NH_) p = qb + (size_t)s * 2048 + hh * 128;
    else          p = kb + (size_t)s * 512 + (hh - NH_) * 128;
    float a = p[d], b = p[d + 64];
    p[d] = a * c0 - b * s0;
    p[d + 64] = b * c1 + a * s1;
  }
}

// ---------------- MFMA flash attention (causal GQA) ----------------
// 4 waves, q-tile 64 (16 rows/wave), KV-tile 64.
// scores^T = mfma(K, Q): lane's 16 values all belong to q-row (lane&15).
// K LDS [64][128] bf16, XOR-swizzled byte^((row&7)<<4); V LDS transposed [128][64].
__global__ __launch_bounds__(256) void attn_mfma_kernel(const float* __restrict__ qb,
                                                        const float* __restrict__ kb,
                                                        const float* __restrict__ vb,
                                                        float* __restrict__ ob) {
  int n = blockIdx.x, qt = blockIdx.y;
  int g = n >> 2;
  int tid = threadIdx.x;
  int wave = tid >> 6, lane = tid & 63;
  int lq = lane & 15, lg4 = lane >> 4;

  __shared__ __align__(16) unsigned short Kls[64 * 128];
  __shared__ __align__(16) unsigned short Vls[128 * 64];
  __shared__ __align__(16) unsigned short Pls[4][16 * 64];
  __shared__ __align__(16) float corr_ls[4][16];
  __shared__ __align__(16) float lsum_ls[4][16];

  int q0 = qt * 64 + wave * 16;
  // Q fragments held in registers for the whole KV loop (B-operand of QK^T)
  bf16x8 qfrag[4];
  {
    const float* qp = qb + (size_t)(q0 + lq) * 2048 + n * 128;
#pragma unroll
    for (int ks = 0; ks < 4; ++ks) {
      float4 a = *(const float4*)&qp[ks * 32 + lg4 * 8];
      float4 b = *(const float4*)&qp[ks * 32 + lg4 * 8 + 4];
      bf16x8 f;
      f[0] = (short)f2bf(a.x); f[1] = (short)f2bf(a.y);
      f[2] = (short)f2bf(a.z); f[3] = (short)f2bf(a.w);
      f[4] = (short)f2bf(b.x); f[5] = (short)f2bf(b.y);
      f[6] = (short)f2bf(b.z); f[7] = (short)f2bf(b.w);
      qfrag[ks] = f;
    }
  }
  f32x4 oacc[8];
#pragma unroll
  for (int i = 0; i < 8; ++i) oacc[i] = (f32x4){0.f, 0.f, 0.f, 0.f};
  float mrow = -1e30f, lrow = 0.f;

  int nt = qt + 1;
  for (int t = 0; t < nt; ++t) {
    int kv0 = t * 64;
    __syncthreads();
    // ---- stage K (row-major swizzled) and V (transposed swizzled), fp32->bf16
#pragma unroll
    for (int it = 0; it < 8; ++it) {
      int idx = it * 256 + tid;
      int r = idx >> 5;
      int c4 = (idx & 31) * 4;
      size_t gbase = (size_t)(kv0 + r) * 512 + g * 128 + c4;
      float4 kv = *(const float4*)&kb[gbase];
      ushort4 u;
      u.x = f2bf(kv.x); u.y = f2bf(kv.y); u.z = f2bf(kv.z); u.w = f2bf(kv.w);
      *(ushort4*)((char*)Kls + ((r * 256 + c4 * 2) ^ ((r & 7) << 4))) = u;
      float4 vv = *(const float4*)&vb[gbase];
      unsigned short vs0 = f2bf(vv.x), vs1 = f2bf(vv.y), vs2 = f2bf(vv.z), vs3 = f2bf(vv.w);
      *(unsigned short*)((char*)Vls + (((c4 + 0) * 128 + r * 2) ^ (((c4 + 0) & 7) << 4))) = vs0;
      *(unsigned short*)((char*)Vls + (((c4 + 1) * 128 + r * 2) ^ (((c4 + 1) & 7) << 4))) = vs1;
      *(unsigned short*)((char*)Vls + (((c4 + 2) * 128 + r * 2) ^ (((c4 + 2) & 7) << 4))) = vs2;
      *(unsigned short*)((char*)Vls + (((c4 + 3) * 128 + r * 2) ^ (((c4 + 3) & 7) << 4))) = vs3;
    }
    __syncthreads();
    // ---- QK^T (scores^T): sacc[kt] rows = k-subindex, col = q
    f32x4 sacc[4];
#pragma unroll
    for (int i = 0; i < 4; ++i) sacc[i] = (f32x4){0.f, 0.f, 0.f, 0.f};
#pragma unroll
    for (int kt = 0; kt < 4; ++kt) {
      int row = kt * 16 + lq;
#pragma unroll
      for (int ks = 0; ks < 4; ++ks) {
        bf16x8 kf = *(const bf16x8*)((const char*)Kls +
                     ((row * 256 + ks * 64 + lg4 * 16) ^ ((row & 7) << 4)));
        sacc[kt] = __builtin_amdgcn_mfma_f32_16x16x32_bf16(kf, qfrag[ks], sacc[kt], 0, 0, 0);
      }
    }
    // ---- online softmax; lane owns q-row (q0+lq), k = kv0 + kt*16 + lg4*4 + r
    int qg = q0 + lq;
    float s[16], p[16];
    float rmax = -1e30f;
#pragma unroll
    for (int kt = 0; kt < 4; ++kt) {
#pragma unroll
      for (int r = 0; r < 4; ++r) {
        int kg = kv0 + kt * 16 + lg4 * 4 + r;
        float v = sacc[kt][r] * SCALE_;
        v = (kg <= qg) ? v : -1e30f;
        s[kt * 4 + r] = v;
        rmax = fmaxf(rmax, v);
      }
    }
    rmax = fmaxf(rmax, __shfl_xor(rmax, 16));
    rmax = fmaxf(rmax, __shfl_xor(rmax, 32));
    float mnew = fmaxf(mrow, rmax);
    float corr = __expf(mrow - mnew);
    float psum = 0.f;
#pragma unroll
    for (int i = 0; i < 16; ++i) { p[i] = __expf(s[i] - mnew); psum += p[i]; }
    psum += __shfl_xor(psum, 16);
    psum += __shfl_xor(psum, 32);
    lrow = lrow * corr + psum;
    mrow = mnew;
    if (lane < 16) corr_ls[wave][lq] = corr;
    // ---- write P (bf16) to per-wave swizzled LDS tile [16 q][64 k]
#pragma unroll
    for (int kt = 0; kt < 4; ++kt) {
      unsigned u0 = (unsigned)f2bf(p[kt * 4 + 0]) | ((unsigned)f2bf(p[kt * 4 + 1]) << 16);
      unsigned u1 = (unsigned)f2bf(p[kt * 4 + 2]) | ((unsigned)f2bf(p[kt * 4 + 3]) << 16);
      int colb = kt * 32 + lg4 * 8;
      *(unsigned*)((char*)&Pls[wave][0] + ((lq * 128 + colb) ^ ((lq & 7) << 4))) = u0;
      *(unsigned*)((char*)&Pls[wave][0] + ((lq * 128 + colb + 4) ^ ((lq & 7) << 4))) = u1;
    }
    // ---- rescale output accumulator by corr (per q-row, via LDS broadcast)
    f32x4 c4v = *(const f32x4*)&corr_ls[wave][lg4 * 4];
#pragma unroll
    for (int dt = 0; dt < 8; ++dt) {
#pragma unroll
      for (int r = 0; r < 4; ++r) oacc[dt][r] *= c4v[r];
    }
    // ---- PV: A = P (from LDS), B = V (transposed LDS)
    bf16x8 pfrag[2];
#pragma unroll
    for (int ks2 = 0; ks2 < 2; ++ks2)
      pfrag[ks2] = *(const bf16x8*)((const char*)&Pls[wave][0] +
                    ((lq * 128 + ks2 * 64 + lg4 * 16) ^ ((lq & 7) << 4)));
#pragma unroll
    for (int dt = 0; dt < 8; ++dt) {
      int dr = dt * 16 + lq;
#pragma unroll
      for (int ks2 = 0; ks2 < 2; ++ks2) {
        bf16x8 vf = *(const bf16x8*)((const char*)Vls +
                     ((dr * 128 + ks2 * 64 + lg4 * 16) ^ ((dr & 7) << 4)));
        oacc[dt] = __builtin_amdgcn_mfma_f32_16x16x32_bf16(pfrag[ks2], vf, oacc[dt], 0, 0, 0);
      }
    }
  }
  if (lane < 16) lsum_ls[wave][lq] = lrow;
  f32x4 l4 = *(const f32x4*)&lsum_ls[wave][lg4 * 4];
#pragma unroll
  for (int dt = 0; dt < 8; ++dt) {
#pragma unroll
    for (int r = 0; r < 4; ++r) {
      ob[(size_t)(q0 + lg4 * 4 + r) * 2048 + n * 128 + dt * 16 + lq] = oacc[dt][r] / l4[r];
    }
  }
}

// ---------------- RMSNorm #2 (row norm then per-head norm) ----------------
__global__ void rmsnorm2_kernel(const float* __restrict__ hin, const float* __restrict__ ln2w,
                                const float* __restrict__ mhw, float* __restrict__ yout) {
  int s = blockIdx.x, tid = threadIdx.x;  // 256
  const float* row = hin + (size_t)s * H_;
  __shared__ float y1[H_];
  __shared__ float red[256];
  __shared__ float ph[16][17];
  float ss = 0.f;
  for (int i = tid; i < H_; i += 256) { float v = row[i]; ss += v * v; }
  red[tid] = ss; __syncthreads();
  for (int off = 128; off > 0; off >>= 1) {
    if (tid < off) red[tid] += red[tid + off];
    __syncthreads();
  }
  float rs1 = rsqrtf(red[0] / H_ + EPS_);
  for (int i = tid; i < H_; i += 256) y1[i] = row[i] * rs1 * ln2w[i];
  __syncthreads();
  int n = tid >> 4, j = tid & 15;
  float s2 = 0.f;
  for (int d = j * 8; d < j * 8 + 8; ++d) { float v = y1[n * 128 + d]; s2 += v * v; }
  ph[n][j] = s2; __syncthreads();
  if (j == 0) {
    float t = 0.f;
    for (int q = 0; q < 16; ++q) t += ph[n][q];
    ph[n][16] = rsqrtf(t / HD_ + EPS_);
  }
  __syncthreads();
  for (int i = tid; i < H_; i += 256) {
    int hn = i >> 7;
    yout[(size_t)s * H_ + i] = y1[i] * ph[hn][16] * mhw[i];
  }
}

// ---------------- router: softmax + top2 + scatter into expert lists ---------
__global__ void route_kernel(const float* __restrict__ yb, const float* __restrict__ rw,
                             int* __restrict__ cnt, int* __restrict__ idxb,
                             float* __restrict__ wtb) {
  int s = blockIdx.x, tid = threadIdx.x;  // 128
  int n = tid >> 3, e = tid & 7;
  const float* yrow = yb + (size_t)s * 2048 + n * 128;
  const float* wrow = rw + (size_t)(n * 8 + e) * 128;
  float lg = 0.f;
  for (int d = 0; d < 128; ++d) lg += yrow[d] * wrow[d];
  float mx = lg;
  for (int off = 1; off < 8; off <<= 1) mx = fmaxf(mx, __shfl_xor(mx, off));
  float p = __expf(lg - mx);
  float sum = p;
  for (int off = 1; off < 8; off <<= 1) sum += __shfl_xor(sum, off);
  float rp = p / sum;
  float v1 = rp; int i1 = e;
  for (int off = 1; off < 8; off <<= 1) {
    float ov = __shfl_xor(v1, off); int oi = __shfl_xor(i1, off);
    if (ov > v1 || (ov == v1 && oi < i1)) { v1 = ov; i1 = oi; }
  }
  float v2 = (e == i1) ? -1e30f : rp; int i2 = e;
  for (int off = 1; off < 8; off <<= 1) {
    float ov = __shfl_xor(v2, off); int oi = __shfl_xor(i2, off);
    if (ov > v2 || (ov == v2 && oi < i2)) { v2 = ov; i2 = oi; }
  }
  if (e == 0) {
    float wsum = v1 + v2;
    int pe1 = n * 8 + i1;
    int pos1 = atomicAdd(&cnt[pe1], 1);
    idxb[pe1 * S_ + pos1] = s; wtb[pe1 * S_ + pos1] = v1 / wsum;
    int pe2 = n * 8 + i2;
    int pos2 = atomicAdd(&cnt[pe2], 1);
    idxb[pe2 * S_ + pos2] = s; wtb[pe2 * S_ + pos2] = v2 / wsum;
  }
}

// ---------------- gathered top-2 expert FFN, accumulate into out -------------
__global__ void ffn_kernel(const float* __restrict__ yb,
                           const float* __restrict__ kw, const float* __restrict__ uw,
                           const float* __restrict__ vw,
                           const int* __restrict__ cnt, const int* __restrict__ idxb,
                           const float* __restrict__ wtb, float* __restrict__ out) {
  int pe = blockIdx.x;  // n*8+e
  int n = pe >> 3, e = pe & 7, g = n >> 2;
  int tid = threadIdx.x;  // 256
  int c = cnt[pe];
  const float* KW = kw + (size_t)((g * 8 + e) * 256) * 128;
  const float* UW = uw + (size_t)((g * 8 + e) * 256) * 128;
  const float* VW = vw + (size_t)((g * 8 + e) * 256) * 128;
  __shared__ float yls[8][128];
  __shared__ float acls[8][256];
  __shared__ int sidx[8];
  __shared__ float swt[8];
  for (int base = blockIdx.y * 8; base < c; base += gridDim.y * 8) {
    int nr = min(8, c - base);
    if (tid < 8) {
      sidx[tid] = (tid < nr) ? idxb[pe * S_ + base + tid] : 0;
      swt[tid] = (tid < nr) ? wtb[pe * S_ + base + tid] : 0.f;
    }
    __syncthreads();
    for (int idx = tid; idx < nr * 128; idx += 256) {
      int r = idx >> 7, d = idx & 127;
      yls[r][d] = yb[(size_t)sidx[r] * 2048 + n * 128 + d];
    }
    __syncthreads();
    {  // phase A: gate/up per f = tid
      int f = tid;
      float ga[8], ua[8];
#pragma unroll
      for (int r = 0; r < 8; ++r) { ga[r] = 0.f; ua[r] = 0.f; }
      const float* kr = KW + (size_t)f * 128;
      const float* ur = UW + (size_t)f * 128;
      for (int d = 0; d < 128; ++d) {
        float kv = kr[d], uv = ur[d];
#pragma unroll
        for (int r = 0; r < 8; ++r) { float yv = yls[r][d]; ga[r] += kv * yv; ua[r] += uv * yv; }
      }
#pragma unroll
      for (int r = 0; r < 8; ++r) {
        float gg = ga[r];
        float sig = 1.f / (1.f + __expf(-gg));
        acls[r][f] = gg * sig * ua[r] * swt[r];
      }
    }
    __syncthreads();
    {  // phase B: down proj, atomic accumulate
      int d = tid & 127, half = tid >> 7;
      float pa[8];
#pragma unroll
      for (int r = 0; r < 8; ++r) pa[r] = 0.f;
      const float* vr = VW + (size_t)half * 128 * 128;
      for (int f = 0; f < 128; ++f) {
        float vv = vr[(size_t)f * 128 + d];
#pragma unroll
        for (int r = 0; r < 8; ++r) pa[r] += acls[r][f + half * 128] * vv;
      }
      for (int r = 0; r < nr; ++r)
        atomicAdd(&out[(size_t)sidx[r] * 2048 + n * 128 + d], pa[r]);
    }
    __syncthreads();
  }
}

extern "C" void kernel_launch(void* const* d_in, const int* in_sizes, int n_in,
                              void* d_out, int out_size, void* d_ws, size_t ws_size,
                              hipStream_t stream) {
  const float* hidden = (const float*)d_in[0];
  const float* cosb   = (const float*)d_in[1];
  const float* sinb   = (const float*)d_in[2];
  // d_in[3] = attn_mask (unused; causal handled analytically)
  const float* ln1w   = (const float*)d_in[4];
  const float* ln2w   = (const float*)d_in[5];
  const float* wq     = (const float*)d_in[6];
  const float* wk     = (const float*)d_in[7];
  const float* wv     = (const float*)d_in[8];
  const float* wo     = (const float*)d_in[9];
  const float* mhw    = (const float*)d_in[10];
  const float* rw     = (const float*)d_in[11];
  const float* kww    = (const float*)d_in[12];
  const float* uww    = (const float*)d_in[13];
  const float* vww    = (const float*)d_in[14];
  float* out = (float*)d_out;

  float* ws = (float*)d_ws;
  float* x     = ws;                  // 2M
  float* qb    = x + 2097152;         // 2M
  float* kb    = qb + 2097152;        // 512K
  float* vb    = kb + 524288;         // 512K
  float* attnb = vb + 524288;         // 2M
  float* yb    = attnb + 2097152;     // 2M
  int*   cntb  = (int*)(yb + 2097152);       // 128
  int*   idxb  = cntb + 128;                 // 128K
  float* wtb   = (float*)(idxb + 131072);    // 128K

  hipMemsetAsync(cntb, 0, 128 * sizeof(int), stream);

  rmsnorm1_kernel<<<S_, 256, 0, stream>>>(hidden, ln1w, x);

  gemm_rt_kernel<<<dim3(2048 / 64, 1024 / 64), 256, 0, stream>>>(x, wq, qb, nullptr, 1024, 2048, 2048);
  gemm_rt_kernel<<<dim3(512 / 64, 1024 / 64), 256, 0, stream>>>(x, wk, kb, nullptr, 1024, 512, 2048);
  gemm_rt_kernel<<<dim3(512 / 64, 1024 / 64), 256, 0, stream>>>(x, wv, vb, nullptr, 1024, 512, 2048);

  rope_kernel<<<S_, 256, 0, stream>>>(qb, kb, cosb, sinb);

  attn_mfma_kernel<<<dim3(NH_, S_ / 64), 256, 0, stream>>>(qb, kb, vb, attnb);

  gemm_rt_kernel<<<dim3(2048 / 64, 1024 / 64), 256, 0, stream>>>(attnb, wo, out, hidden, 1024, 2048, 2048);

  rmsnorm2_kernel<<<S_, 256, 0, stream>>>(out, ln2w, mhw, yb);

  route_kernel<<<S_, 128, 0, stream>>>(yb, rw, cntb, idxb, wtb);

  ffn_kernel<<<dim3(NH_ * E_, 16), 256, 0, stream>>>(yb, kww, uww, vww, cntb, idxb, wtb, out);
}

// Round 4
// 461.592 us; speedup vs baseline: 5.4640x; 2.2109x over previous
//
#include <hip/hip_runtime.h>
#include <hip/hip_bf16.h>

#define S_ 1024
#define H_ 2048
#define NH_ 16
#define NKV_ 4
#define HD_ 128
#define E_ 8
#define F_ 256
#define EPS_ 1e-6f
#define SCALE_ 0.08838834764831845f  // 128^-0.5

typedef __attribute__((ext_vector_type(8))) short bf16x8;
typedef __attribute__((ext_vector_type(4))) float f32x4;

static __device__ __forceinline__ unsigned short f2bf(float x) {
  unsigned u = __float_as_uint(x);
  unsigned r = (u + 0x7FFFu + ((u >> 16) & 1u)) >> 16;
  return (unsigned short)r;
}
static __device__ __forceinline__ float bf2f(unsigned short b) {
  return __uint_as_float(((unsigned)b) << 16);
}
// conversion via HIP intrinsic (compiler can fuse pairs into v_cvt_pk_bf16_f32)
static __device__ __forceinline__ unsigned short f2bh(float x) {
  __hip_bfloat16 b = __float2bfloat16(x);
  return *reinterpret_cast<unsigned short*>(&b);
}

// ---------------- RMSNorm #1 ----------------
__global__ void rmsnorm1_kernel(const float* __restrict__ in, const float* __restrict__ w,
                                float* __restrict__ out) {
  int s = blockIdx.x, tid = threadIdx.x;
  const float* row = in + s * H_;
  __shared__ float red[256];
  float ss = 0.f;
  for (int i = tid; i < H_; i += 256) { float v = row[i]; ss += v * v; }
  red[tid] = ss; __syncthreads();
  for (int off = 128; off > 0; off >>= 1) {
    if (tid < off) red[tid] += red[tid + off];
    __syncthreads();
  }
  float rs = rsqrtf(red[0] / H_ + EPS_);
  for (int i = tid; i < H_; i += 256) out[s * H_ + i] = row[i] * rs * w[i];
}

// ============ bf16 MFMA GEMM building blocks ============
// C[M,N] = A[M,K] @ B[N,K]^T. 128x128 tile, BK=64, 4 waves (2x2 of 64x64).
// LDS tiles [128 rows][64 k] bf16, XOR swizzle byte^((row&7)<<4).

// ---- fused QKV: A = x [1024 x 2048]; B rows 0..2047 wq, 2048..2559 wk, 2560..3071 wv
__global__ __launch_bounds__(256) void qkv_mfma_kernel(const float* __restrict__ A,
                                                       const float* __restrict__ wq,
                                                       const float* __restrict__ wk,
                                                       const float* __restrict__ wv,
                                                       float* __restrict__ qb,
                                                       float* __restrict__ kb,
                                                       float* __restrict__ vb) {
  int bm = blockIdx.y * 128;
  int bn = blockIdx.x * 128;
  const float* B; float* C; int ldc, cb;
  if (bn < 2048)      { B = wq + (size_t)bn * 2048;          C = qb; ldc = 2048; cb = bn; }
  else if (bn < 2560) { B = wk + (size_t)(bn - 2048) * 2048; C = kb; ldc = 512;  cb = bn - 2048; }
  else                { B = wv + (size_t)(bn - 2560) * 2048; C = vb; ldc = 512;  cb = bn - 2560; }
  int tid = threadIdx.x, wave = tid >> 6, lane = tid & 63;
  int lq = lane & 15, lg4 = lane >> 4;
  int wr = (wave >> 1) * 64, wc = (wave & 1) * 64;
  __shared__ __align__(16) unsigned short Als[128 * 64];
  __shared__ __align__(16) unsigned short Bls[128 * 64];
  f32x4 acc[4][4];
#pragma unroll
  for (int i = 0; i < 4; ++i)
#pragma unroll
    for (int j = 0; j < 4; ++j) acc[i][j] = (f32x4){0.f, 0.f, 0.f, 0.f};
  for (int k0 = 0; k0 < 2048; k0 += 64) {
    __syncthreads();
#pragma unroll
    for (int it = 0; it < 8; ++it) {
      int idx = it * 256 + tid;
      int r = idx >> 4, c4 = (idx & 15) * 4;
      float4 av = *(const float4*)&A[(size_t)(bm + r) * 2048 + k0 + c4];
      ushort4 ua; ua.x = f2bh(av.x); ua.y = f2bh(av.y); ua.z = f2bh(av.z); ua.w = f2bh(av.w);
      *(ushort4*)((char*)Als + ((r * 128 + c4 * 2) ^ ((r & 7) << 4))) = ua;
      float4 bv = *(const float4*)&B[(size_t)r * 2048 + k0 + c4];
      ushort4 ub; ub.x = f2bh(bv.x); ub.y = f2bh(bv.y); ub.z = f2bh(bv.z); ub.w = f2bh(bv.w);
      *(ushort4*)((char*)Bls + ((r * 128 + c4 * 2) ^ ((r & 7) << 4))) = ub;
    }
    __syncthreads();
#pragma unroll
    for (int ks = 0; ks < 2; ++ks) {
      bf16x8 af[4], bfr[4];
#pragma unroll
      for (int mi = 0; mi < 4; ++mi) {
        int row = wr + mi * 16 + lq;
        af[mi] = *(const bf16x8*)((const char*)Als + ((row * 128 + ks * 64 + lg4 * 16) ^ ((row & 7) << 4)));
      }
#pragma unroll
      for (int ni = 0; ni < 4; ++ni) {
        int row = wc + ni * 16 + lq;
        bfr[ni] = *(const bf16x8*)((const char*)Bls + ((row * 128 + ks * 64 + lg4 * 16) ^ ((row & 7) << 4)));
      }
#pragma unroll
      for (int mi = 0; mi < 4; ++mi)
#pragma unroll
        for (int ni = 0; ni < 4; ++ni)
          acc[mi][ni] = __builtin_amdgcn_mfma_f32_16x16x32_bf16(af[mi], bfr[ni], acc[mi][ni], 0, 0, 0);
    }
  }
#pragma unroll
  for (int mi = 0; mi < 4; ++mi)
#pragma unroll
    for (int ni = 0; ni < 4; ++ni) {
      int col = cb + wc + ni * 16 + lq;
#pragma unroll
      for (int reg = 0; reg < 4; ++reg) {
        int m = bm + wr + mi * 16 + lg4 * 4 + reg;
        C[(size_t)m * ldc + col] = acc[mi][ni][reg];
      }
    }
}

// ---- WO GEMM with residual: out[M,N] = attn[M,K] @ wo[N,K]^T + hidden
__global__ __launch_bounds__(256) void wo_mfma_kernel(const float* __restrict__ A,
                                                      const float* __restrict__ Bmat,
                                                      const float* __restrict__ resid,
                                                      float* __restrict__ C) {
  int bm = blockIdx.y * 128;
  int bn = blockIdx.x * 128;
  int tid = threadIdx.x, wave = tid >> 6, lane = tid & 63;
  int lq = lane & 15, lg4 = lane >> 4;
  int wr = (wave >> 1) * 64, wc = (wave & 1) * 64;
  __shared__ __align__(16) unsigned short Als[128 * 64];
  __shared__ __align__(16) unsigned short Bls[128 * 64];
  f32x4 acc[4][4];
#pragma unroll
  for (int i = 0; i < 4; ++i)
#pragma unroll
    for (int j = 0; j < 4; ++j) acc[i][j] = (f32x4){0.f, 0.f, 0.f, 0.f};
  for (int k0 = 0; k0 < 2048; k0 += 64) {
    __syncthreads();
#pragma unroll
    for (int it = 0; it < 8; ++it) {
      int idx = it * 256 + tid;
      int r = idx >> 4, c4 = (idx & 15) * 4;
      float4 av = *(const float4*)&A[(size_t)(bm + r) * 2048 + k0 + c4];
      ushort4 ua; ua.x = f2bh(av.x); ua.y = f2bh(av.y); ua.z = f2bh(av.z); ua.w = f2bh(av.w);
      *(ushort4*)((char*)Als + ((r * 128 + c4 * 2) ^ ((r & 7) << 4))) = ua;
      float4 bv = *(const float4*)&Bmat[(size_t)(bn + r) * 2048 + k0 + c4];
      ushort4 ub; ub.x = f2bh(bv.x); ub.y = f2bh(bv.y); ub.z = f2bh(bv.z); ub.w = f2bh(bv.w);
      *(ushort4*)((char*)Bls + ((r * 128 + c4 * 2) ^ ((r & 7) << 4))) = ub;
    }
    __syncthreads();
#pragma unroll
    for (int ks = 0; ks < 2; ++ks) {
      bf16x8 af[4], bfr[4];
#pragma unroll
      for (int mi = 0; mi < 4; ++mi) {
        int row = wr + mi * 16 + lq;
        af[mi] = *(const bf16x8*)((const char*)Als + ((row * 128 + ks * 64 + lg4 * 16) ^ ((row & 7) << 4)));
      }
#pragma unroll
      for (int ni = 0; ni < 4; ++ni) {
        int row = wc + ni * 16 + lq;
        bfr[ni] = *(const bf16x8*)((const char*)Bls + ((row * 128 + ks * 64 + lg4 * 16) ^ ((row & 7) << 4)));
      }
#pragma unroll
      for (int mi = 0; mi < 4; ++mi)
#pragma unroll
        for (int ni = 0; ni < 4; ++ni)
          acc[mi][ni] = __builtin_amdgcn_mfma_f32_16x16x32_bf16(af[mi], bfr[ni], acc[mi][ni], 0, 0, 0);
    }
  }
#pragma unroll
  for (int mi = 0; mi < 4; ++mi)
#pragma unroll
    for (int ni = 0; ni < 4; ++ni) {
      int col = bn + wc + ni * 16 + lq;
#pragma unroll
      for (int reg = 0; reg < 4; ++reg) {
        int m = bm + wr + mi * 16 + lg4 * 4 + reg;
        C[(size_t)m * 2048 + col] = acc[mi][ni][reg] + resid[(size_t)m * 2048 + col];
      }
    }
}

// ---------------- RoPE (in place on q and k) ----------------
__global__ void rope_kernel(float* __restrict__ qb, float* __restrict__ kb,
                            const float* __restrict__ cosb, const float* __restrict__ sinb) {
  int s = blockIdx.x, tid = threadIdx.x;
  for (int idx = tid; idx < (NH_ + NKV_) * 64; idx += 256) {
    int hh = idx >> 6;
    int d = idx & 63;
    float c0 = cosb[s * HD_ + d], s0 = sinb[s * HD_ + d];
    float c1 = cosb[s * HD_ + d + 64], s1 = sinb[s * HD_ + d + 64];
    float* p;
    if (hh < NH_) p = qb + (size_t)s * 2048 + hh * 128;
    else          p = kb + (size_t)s * 512 + (hh - NH_) * 128;
    float a = p[d], b = p[d + 64];
    p[d] = a * c0 - b * s0;
    p[d + 64] = b * c1 + a * s1;
  }
}

// ---------------- MFMA flash attention (causal GQA) ----------------
__global__ __launch_bounds__(256) void attn_mfma_kernel(const float* __restrict__ qb,
                                                        const float* __restrict__ kb,
                                                        const float* __restrict__ vb,
                                                        float* __restrict__ ob) {
  int n = blockIdx.x, qt = blockIdx.y;
  int g = n >> 2;
  int tid = threadIdx.x;
  int wave = tid >> 6, lane = tid & 63;
  int lq = lane & 15, lg4 = lane >> 4;

  __shared__ __align__(16) unsigned short Kls[64 * 128];
  __shared__ __align__(16) unsigned short Vls[128 * 64];
  __shared__ __align__(16) unsigned short Pls[4][16 * 64];
  __shared__ __align__(16) float corr_ls[4][16];
  __shared__ __align__(16) float lsum_ls[4][16];

  int q0 = qt * 64 + wave * 16;
  bf16x8 qfrag[4];
  {
    const float* qp = qb + (size_t)(q0 + lq) * 2048 + n * 128;
#pragma unroll
    for (int ks = 0; ks < 4; ++ks) {
      float4 a = *(const float4*)&qp[ks * 32 + lg4 * 8];
      float4 b = *(const float4*)&qp[ks * 32 + lg4 * 8 + 4];
      bf16x8 f;
      f[0] = (short)f2bf(a.x); f[1] = (short)f2bf(a.y);
      f[2] = (short)f2bf(a.z); f[3] = (short)f2bf(a.w);
      f[4] = (short)f2bf(b.x); f[5] = (short)f2bf(b.y);
      f[6] = (short)f2bf(b.z); f[7] = (short)f2bf(b.w);
      qfrag[ks] = f;
    }
  }
  f32x4 oacc[8];
#pragma unroll
  for (int i = 0; i < 8; ++i) oacc[i] = (f32x4){0.f, 0.f, 0.f, 0.f};
  float mrow = -1e30f, lrow = 0.f;

  int nt = qt + 1;
  for (int t = 0; t < nt; ++t) {
    int kv0 = t * 64;
    __syncthreads();
#pragma unroll
    for (int it = 0; it < 8; ++it) {
      int idx = it * 256 + tid;
      int r = idx >> 5;
      int c4 = (idx & 31) * 4;
      size_t gbase = (size_t)(kv0 + r) * 512 + g * 128 + c4;
      float4 kv = *(const float4*)&kb[gbase];
      ushort4 u;
      u.x = f2bf(kv.x); u.y = f2bf(kv.y); u.z = f2bf(kv.z); u.w = f2bf(kv.w);
      *(ushort4*)((char*)Kls + ((r * 256 + c4 * 2) ^ ((r & 7) << 4))) = u;
      float4 vv = *(const float4*)&vb[gbase];
      unsigned short vs0 = f2bf(vv.x), vs1 = f2bf(vv.y), vs2 = f2bf(vv.z), vs3 = f2bf(vv.w);
      *(unsigned short*)((char*)Vls + (((c4 + 0) * 128 + r * 2) ^ (((c4 + 0) & 7) << 4))) = vs0;
      *(unsigned short*)((char*)Vls + (((c4 + 1) * 128 + r * 2) ^ (((c4 + 1) & 7) << 4))) = vs1;
      *(unsigned short*)((char*)Vls + (((c4 + 2) * 128 + r * 2) ^ (((c4 + 2) & 7) << 4))) = vs2;
      *(unsigned short*)((char*)Vls + (((c4 + 3) * 128 + r * 2) ^ (((c4 + 3) & 7) << 4))) = vs3;
    }
    __syncthreads();
    f32x4 sacc[4];
#pragma unroll
    for (int i = 0; i < 4; ++i) sacc[i] = (f32x4){0.f, 0.f, 0.f, 0.f};
#pragma unroll
    for (int kt = 0; kt < 4; ++kt) {
      int row = kt * 16 + lq;
#pragma unroll
      for (int ks = 0; ks < 4; ++ks) {
        bf16x8 kf = *(const bf16x8*)((const char*)Kls +
                     ((row * 256 + ks * 64 + lg4 * 16) ^ ((row & 7) << 4)));
        sacc[kt] = __builtin_amdgcn_mfma_f32_16x16x32_bf16(kf, qfrag[ks], sacc[kt], 0, 0, 0);
      }
    }
    int qg = q0 + lq;
    float s[16], p[16];
    float rmax = -1e30f;
#pragma unroll
    for (int kt = 0; kt < 4; ++kt) {
#pragma unroll
      for (int r = 0; r < 4; ++r) {
        int kg = kv0 + kt * 16 + lg4 * 4 + r;
        float v = sacc[kt][r] * SCALE_;
        v = (kg <= qg) ? v : -1e30f;
        s[kt * 4 + r] = v;
        rmax = fmaxf(rmax, v);
      }
    }
    rmax = fmaxf(rmax, __shfl_xor(rmax, 16));
    rmax = fmaxf(rmax, __shfl_xor(rmax, 32));
    float mnew = fmaxf(mrow, rmax);
    float corr = __expf(mrow - mnew);
    float psum = 0.f;
#pragma unroll
    for (int i = 0; i < 16; ++i) { p[i] = __expf(s[i] - mnew); psum += p[i]; }
    psum += __shfl_xor(psum, 16);
    psum += __shfl_xor(psum, 32);
    lrow = lrow * corr + psum;
    mrow = mnew;
    if (lane < 16) corr_ls[wave][lq] = corr;
#pragma unroll
    for (int kt = 0; kt < 4; ++kt) {
      unsigned u0 = (unsigned)f2bf(p[kt * 4 + 0]) | ((unsigned)f2bf(p[kt * 4 + 1]) << 16);
      unsigned u1 = (unsigned)f2bf(p[kt * 4 + 2]) | ((unsigned)f2bf(p[kt * 4 + 3]) << 16);
      int colb = kt * 32 + lg4 * 8;
      *(unsigned*)((char*)&Pls[wave][0] + ((lq * 128 + colb) ^ ((lq & 7) << 4))) = u0;
      *(unsigned*)((char*)&Pls[wave][0] + ((lq * 128 + colb + 4) ^ ((lq & 7) << 4))) = u1;
    }
    f32x4 c4v = *(const f32x4*)&corr_ls[wave][lg4 * 4];
#pragma unroll
    for (int dt = 0; dt < 8; ++dt) {
#pragma unroll
      for (int r = 0; r < 4; ++r) oacc[dt][r] *= c4v[r];
    }
    bf16x8 pfrag[2];
#pragma unroll
    for (int ks2 = 0; ks2 < 2; ++ks2)
      pfrag[ks2] = *(const bf16x8*)((const char*)&Pls[wave][0] +
                    ((lq * 128 + ks2 * 64 + lg4 * 16) ^ ((lq & 7) << 4)));
#pragma unroll
    for (int dt = 0; dt < 8; ++dt) {
      int dr = dt * 16 + lq;
#pragma unroll
      for (int ks2 = 0; ks2 < 2; ++ks2) {
        bf16x8 vf = *(const bf16x8*)((const char*)Vls +
                     ((dr * 128 + ks2 * 64 + lg4 * 16) ^ ((dr & 7) << 4)));
        oacc[dt] = __builtin_amdgcn_mfma_f32_16x16x32_bf16(pfrag[ks2], vf, oacc[dt], 0, 0, 0);
      }
    }
  }
  if (lane < 16) lsum_ls[wave][lq] = lrow;
  f32x4 l4 = *(const f32x4*)&lsum_ls[wave][lg4 * 4];
#pragma unroll
  for (int dt = 0; dt < 8; ++dt) {
#pragma unroll
    for (int r = 0; r < 4; ++r) {
      ob[(size_t)(q0 + lg4 * 4 + r) * 2048 + n * 128 + dt * 16 + lq] = oacc[dt][r] / l4[r];
    }
  }
}

// ---------------- RMSNorm #2 (row norm then per-head norm) ----------------
__global__ void rmsnorm2_kernel(const float* __restrict__ hin, const float* __restrict__ ln2w,
                                const float* __restrict__ mhw, float* __restrict__ yout) {
  int s = blockIdx.x, tid = threadIdx.x;  // 256
  const float* row = hin + (size_t)s * H_;
  __shared__ float y1[H_];
  __shared__ float red[256];
  __shared__ float ph[16][17];
  float ss = 0.f;
  for (int i = tid; i < H_; i += 256) { float v = row[i]; ss += v * v; }
  red[tid] = ss; __syncthreads();
  for (int off = 128; off > 0; off >>= 1) {
    if (tid < off) red[tid] += red[tid + off];
    __syncthreads();
  }
  float rs1 = rsqrtf(red[0] / H_ + EPS_);
  for (int i = tid; i < H_; i += 256) y1[i] = row[i] * rs1 * ln2w[i];
  __syncthreads();
  int n = tid >> 4, j = tid & 15;
  float s2 = 0.f;
  for (int d = j * 8; d < j * 8 + 8; ++d) { float v = y1[n * 128 + d]; s2 += v * v; }
  ph[n][j] = s2; __syncthreads();
  if (j == 0) {
    float t = 0.f;
    for (int q = 0; q < 16; ++q) t += ph[n][q];
    ph[n][16] = rsqrtf(t / HD_ + EPS_);
  }
  __syncthreads();
  for (int i = tid; i < H_; i += 256) {
    int hn = i >> 7;
    yout[(size_t)s * H_ + i] = y1[i] * ph[hn][16] * mhw[i];
  }
}

// ---------------- router: softmax + top2 + scatter into expert lists ---------
__global__ void route_kernel(const float* __restrict__ yb, const float* __restrict__ rw,
                             int* __restrict__ cnt, int* __restrict__ idxb,
                             float* __restrict__ wtb) {
  int s = blockIdx.x, tid = threadIdx.x;  // 128
  int n = tid >> 3, e = tid & 7;
  const float* yrow = yb + (size_t)s * 2048 + n * 128;
  const float* wrow = rw + (size_t)(n * 8 + e) * 128;
  float lg = 0.f;
  for (int d = 0; d < 128; ++d) lg += yrow[d] * wrow[d];
  float mx = lg;
  for (int off = 1; off < 8; off <<= 1) mx = fmaxf(mx, __shfl_xor(mx, off));
  float p = __expf(lg - mx);
  float sum = p;
  for (int off = 1; off < 8; off <<= 1) sum += __shfl_xor(sum, off);
  float rp = p / sum;
  float v1 = rp; int i1 = e;
  for (int off = 1; off < 8; off <<= 1) {
    float ov = __shfl_xor(v1, off); int oi = __shfl_xor(i1, off);
    if (ov > v1 || (ov == v1 && oi < i1)) { v1 = ov; i1 = oi; }
  }
  float v2 = (e == i1) ? -1e30f : rp; int i2 = e;
  for (int off = 1; off < 8; off <<= 1) {
    float ov = __shfl_xor(v2, off); int oi = __shfl_xor(i2, off);
    if (ov > v2 || (ov == v2 && oi < i2)) { v2 = ov; i2 = oi; }
  }
  if (e == 0) {
    float wsum = v1 + v2;
    int pe1 = n * 8 + i1;
    int pos1 = atomicAdd(&cnt[pe1], 1);
    idxb[pe1 * S_ + pos1] = s; wtb[pe1 * S_ + pos1] = v1 / wsum;
    int pe2 = n * 8 + i2;
    int pos2 = atomicAdd(&cnt[pe2], 1);
    idxb[pe2 * S_ + pos2] = s; wtb[pe2 * S_ + pos2] = v2 / wsum;
  }
}

// ---------------- MoE FFN via MFMA: block = (pe, 64-token chunk) -------------
// gate/up: [64x128] @ KW/UW[256x128]^T (4 staged 64-row chunks, K=128)
// act = silu(gate)*up*wt -> bf16 LDS [64][256]
// down: [64x256] @ VW^T (VW staged transposed per 64-f chunk), atomicAdd to out
__global__ __launch_bounds__(256) void moe_ffn_mfma_kernel(
    const float* __restrict__ yb, const float* __restrict__ kw,
    const float* __restrict__ uw, const float* __restrict__ vw,
    const int* __restrict__ cnt, const int* __restrict__ idxb,
    const float* __restrict__ wtb, float* __restrict__ out) {
  int pe = blockIdx.x;
  int c = cnt[pe];
  int base = blockIdx.y * 64;
  if (base >= c) return;
  int n = pe >> 3, e = pe & 7, g = n >> 2;
  int nr = min(64, c - base);
  int tid = threadIdx.x, wave = tid >> 6, lane = tid & 63;
  int lq = lane & 15, lg4 = lane >> 4;

  const float* KW = kw + (size_t)((g * 8 + e) * 256) * 128;
  const float* UW = uw + (size_t)((g * 8 + e) * 256) * 128;
  const float* VW = vw + (size_t)((g * 8 + e) * 256) * 128;

  __shared__ __align__(16) unsigned short Yls[64 * 128];   // rows 256B, swz
  __shared__ __align__(16) unsigned short Wst[64 * 128];   // staging: KW/UW rows 256B | VWt rows 128B
  __shared__ __align__(16) unsigned short Act[64 * 256];   // rows 512B, swz
  __shared__ int sidx[64];
  __shared__ float swt[64];

  if (tid < 64) {
    sidx[tid] = (tid < nr) ? idxb[pe * S_ + base + tid] : 0;
    swt[tid]  = (tid < nr) ? wtb[pe * S_ + base + tid] : 0.f;
  }
  __syncthreads();
  // stage gathered Y rows [64][128] fp32->bf16
#pragma unroll
  for (int it = 0; it < 8; ++it) {
    int idx = it * 256 + tid;
    int r = idx >> 5, c4 = (idx & 31) * 4;
    ushort4 u = {0, 0, 0, 0};
    if (r < nr) {
      float4 yv = *(const float4*)&yb[(size_t)sidx[r] * 2048 + n * 128 + c4];
      u.x = f2bh(yv.x); u.y = f2bh(yv.y); u.z = f2bh(yv.z); u.w = f2bh(yv.w);
    }
    *(ushort4*)((char*)Yls + ((r * 256 + c4 * 2) ^ ((r & 7) << 4))) = u;
  }

  // ---- gate/up over 4 f-chunks of 64
  for (int fc = 0; fc < 4; ++fc) {
    // stage KW chunk
    __syncthreads();
#pragma unroll
    for (int it = 0; it < 8; ++it) {
      int idx = it * 256 + tid;
      int r = idx >> 5, c4 = (idx & 31) * 4;
      float4 wv = *(const float4*)&KW[(size_t)(fc * 64 + r) * 128 + c4];
      ushort4 u; u.x = f2bh(wv.x); u.y = f2bh(wv.y); u.z = f2bh(wv.z); u.w = f2bh(wv.w);
      *(ushort4*)((char*)Wst + ((r * 256 + c4 * 2) ^ ((r & 7) << 4))) = u;
    }
    __syncthreads();
    f32x4 gacc[4];
#pragma unroll
    for (int i = 0; i < 4; ++i) gacc[i] = (f32x4){0.f, 0.f, 0.f, 0.f};
#pragma unroll
    for (int ks = 0; ks < 4; ++ks) {
      int arow = wave * 16 + lq;
      bf16x8 a = *(const bf16x8*)((const char*)Yls + ((arow * 256 + ks * 64 + lg4 * 16) ^ ((arow & 7) << 4)));
#pragma unroll
      for (int nf = 0; nf < 4; ++nf) {
        int brow = nf * 16 + lq;
        bf16x8 b = *(const bf16x8*)((const char*)Wst + ((brow * 256 + ks * 64 + lg4 * 16) ^ ((brow & 7) << 4)));
        gacc[nf] = __builtin_amdgcn_mfma_f32_16x16x32_bf16(a, b, gacc[nf], 0, 0, 0);
      }
    }
    // stage UW chunk
    __syncthreads();
#pragma unroll
    for (int it = 0; it < 8; ++it) {
      int idx = it * 256 + tid;
      int r = idx >> 5, c4 = (idx & 31) * 4;
      float4 wv = *(const float4*)&UW[(size_t)(fc * 64 + r) * 128 + c4];
      ushort4 u; u.x = f2bh(wv.x); u.y = f2bh(wv.y); u.z = f2bh(wv.z); u.w = f2bh(wv.w);
      *(ushort4*)((char*)Wst + ((r * 256 + c4 * 2) ^ ((r & 7) << 4))) = u;
    }
    __syncthreads();
    f32x4 uacc[4];
#pragma unroll
    for (int i = 0; i < 4; ++i) uacc[i] = (f32x4){0.f, 0.f, 0.f, 0.f};
#pragma unroll
    for (int ks = 0; ks < 4; ++ks) {
      int arow = wave * 16 + lq;
      bf16x8 a = *(const bf16x8*)((const char*)Yls + ((arow * 256 + ks * 64 + lg4 * 16) ^ ((arow & 7) << 4)));
#pragma unroll
      for (int nf = 0; nf < 4; ++nf) {
        int brow = nf * 16 + lq;
        bf16x8 b = *(const bf16x8*)((const char*)Wst + ((brow * 256 + ks * 64 + lg4 * 16) ^ ((brow & 7) << 4)));
        uacc[nf] = __builtin_amdgcn_mfma_f32_16x16x32_bf16(a, b, uacc[nf], 0, 0, 0);
      }
    }
    // combine -> Act slice [64 tokens][fc*64 .. fc*64+64]
    float wts[4];
#pragma unroll
    for (int reg = 0; reg < 4; ++reg) wts[reg] = swt[wave * 16 + lg4 * 4 + reg];
#pragma unroll
    for (int nf = 0; nf < 4; ++nf) {
#pragma unroll
      for (int reg = 0; reg < 4; ++reg) {
        int m = wave * 16 + lg4 * 4 + reg;
        int f = fc * 64 + nf * 16 + lq;
        float gg = gacc[nf][reg];
        float uu = uacc[nf][reg];
        float sig = 1.f / (1.f + __expf(-gg));
        float av = gg * sig * uu * wts[reg];
        *(unsigned short*)((char*)Act + ((m * 512 + f * 2) ^ ((m & 7) << 4))) = f2bh(av);
      }
    }
  }

  // ---- down proj: C[64][128] = Act[64][256] @ VW[256][128]
  f32x4 dacc[8];
#pragma unroll
  for (int i = 0; i < 8; ++i) dacc[i] = (f32x4){0.f, 0.f, 0.f, 0.f};
  for (int fc = 0; fc < 4; ++fc) {
    __syncthreads();
    // stage VW chunk transposed: Wst[d 0..127][f-local 0..63], rows 128B
#pragma unroll
    for (int it = 0; it < 8; ++it) {
      int idx = it * 256 + tid;
      int r = idx >> 5, c4 = (idx & 31) * 4;  // r = f-local, c4 = d
      float4 wv = *(const float4*)&VW[(size_t)(fc * 64 + r) * 128 + c4];
      unsigned short w0 = f2bh(wv.x), w1 = f2bh(wv.y), w2 = f2bh(wv.z), w3 = f2bh(wv.w);
      *(unsigned short*)((char*)Wst + (((c4 + 0) * 128 + r * 2) ^ (((c4 + 0) & 7) << 4))) = w0;
      *(unsigned short*)((char*)Wst + (((c4 + 1) * 128 + r * 2) ^ (((c4 + 1) & 7) << 4))) = w1;
      *(unsigned short*)((char*)Wst + (((c4 + 2) * 128 + r * 2) ^ (((c4 + 2) & 7) << 4))) = w2;
      *(unsigned short*)((char*)Wst + (((c4 + 3) * 128 + r * 2) ^ (((c4 + 3) & 7) << 4))) = w3;
    }
    __syncthreads();
#pragma unroll
    for (int ks = 0; ks < 2; ++ks) {
      int arow = wave * 16 + lq;
      bf16x8 a = *(const bf16x8*)((const char*)Act +
                  ((arow * 512 + (fc * 64 + ks * 32 + lg4 * 8) * 2) ^ ((arow & 7) << 4)));
#pragma unroll
      for (int nd = 0; nd < 8; ++nd) {
        int drow = nd * 16 + lq;
        bf16x8 b = *(const bf16x8*)((const char*)Wst + ((drow * 128 + ks * 64 + lg4 * 16) ^ ((drow & 7) << 4)));
        dacc[nd] = __builtin_amdgcn_mfma_f32_16x16x32_bf16(a, b, dacc[nd], 0, 0, 0);
      }
    }
  }
  // epilogue: atomic accumulate into out
#pragma unroll
  for (int nd = 0; nd < 8; ++nd) {
    int d = nd * 16 + lq;
#pragma unroll
    for (int reg = 0; reg < 4; ++reg) {
      int mloc = wave * 16 + lg4 * 4 + reg;
      if (mloc < nr) {
        atomicAdd(&out[(size_t)sidx[mloc] * 2048 + n * 128 + d], dacc[nd][reg]);
      }
    }
  }
}

extern "C" void kernel_launch(void* const* d_in, const int* in_sizes, int n_in,
                              void* d_out, int out_size, void* d_ws, size_t ws_size,
                              hipStream_t stream) {
  const float* hidden = (const float*)d_in[0];
  const float* cosb   = (const float*)d_in[1];
  const float* sinb   = (const float*)d_in[2];
  // d_in[3] = attn_mask (unused; causal handled analytically)
  const float* ln1w   = (const float*)d_in[4];
  const float* ln2w   = (const float*)d_in[5];
  const float* wq     = (const float*)d_in[6];
  const float* wk     = (const float*)d_in[7];
  const float* wv     = (const float*)d_in[8];
  const float* wo     = (const float*)d_in[9];
  const float* mhw    = (const float*)d_in[10];
  const float* rw     = (const float*)d_in[11];
  const float* kww    = (const float*)d_in[12];
  const float* uww    = (const float*)d_in[13];
  const float* vww    = (const float*)d_in[14];
  float* out = (float*)d_out;

  float* ws = (float*)d_ws;
  float* x     = ws;                  // 2M floats? no: 1024*2048 = 2M elems
  float* qb    = x + 2097152;
  float* kb    = qb + 2097152;
  float* vb    = kb + 524288;
  float* attnb = vb + 524288;
  float* yb    = attnb + 2097152;
  int*   cntb  = (int*)(yb + 2097152);
  int*   idxb  = cntb + 128;
  float* wtb   = (float*)(idxb + 131072);

  hipMemsetAsync(cntb, 0, 128 * sizeof(int), stream);

  rmsnorm1_kernel<<<S_, 256, 0, stream>>>(hidden, ln1w, x);

  qkv_mfma_kernel<<<dim3(24, 8), 256, 0, stream>>>(x, wq, wk, wv, qb, kb, vb);

  rope_kernel<<<S_, 256, 0, stream>>>(qb, kb, cosb, sinb);

  attn_mfma_kernel<<<dim3(NH_, S_ / 64), 256, 0, stream>>>(qb, kb, vb, attnb);

  wo_mfma_kernel<<<dim3(16, 8), 256, 0, stream>>>(attnb, wo, hidden, out);

  rmsnorm2_kernel<<<S_, 256, 0, stream>>>(out, ln2w, mhw, yb);

  route_kernel<<<S_, 128, 0, stream>>>(yb, rw, cntb, idxb, wtb);

  moe_ffn_mfma_kernel<<<dim3(128, 16), 256, 0, stream>>>(yb, kww, uww, vww, cntb, idxb, wtb, out);
}

// Round 5
// 437.683 us; speedup vs baseline: 5.7625x; 1.0546x over previous
//
#include <hip/hip_runtime.h>
#include <hip/hip_bf16.h>

#define S_ 1024
#define H_ 2048
#define NH_ 16
#define NKV_ 4
#define HD_ 128
#define E_ 8
#define F_ 256
#define EPS_ 1e-6f
#define SCALE_ 0.08838834764831845f  // 128^-0.5

typedef __attribute__((ext_vector_type(8))) short bf16x8;
typedef __attribute__((ext_vector_type(4))) float f32x4;

static __device__ __forceinline__ unsigned short f2bf(float x) {
  unsigned u = __float_as_uint(x);
  unsigned r = (u + 0x7FFFu + ((u >> 16) & 1u)) >> 16;
  return (unsigned short)r;
}
static __device__ __forceinline__ float bf2f(unsigned short b) {
  return __uint_as_float(((unsigned)b) << 16);
}
static __device__ __forceinline__ unsigned short f2bh(float x) {
  __hip_bfloat16 b = __float2bfloat16(x);
  return *reinterpret_cast<unsigned short*>(&b);
}

// ---------------- RMSNorm #1 ----------------
__global__ void rmsnorm1_kernel(const float* __restrict__ in, const float* __restrict__ w,
                                float* __restrict__ out) {
  int s = blockIdx.x, tid = threadIdx.x;
  const float* row = in + s * H_;
  __shared__ float red[256];
  float ss = 0.f;
  for (int i = tid; i < H_; i += 256) { float v = row[i]; ss += v * v; }
  red[tid] = ss; __syncthreads();
  for (int off = 128; off > 0; off >>= 1) {
    if (tid < off) red[tid] += red[tid + off];
    __syncthreads();
  }
  float rs = rsqrtf(red[0] / H_ + EPS_);
  for (int i = tid; i < H_; i += 256) out[s * H_ + i] = row[i] * rs * w[i];
}

// ---------------- weight prep: kw/uw fp32 -> bf16 ----------------
__global__ __launch_bounds__(256) void convert_kuw_kernel(const float* __restrict__ kw,
                                                          const float* __restrict__ uw,
                                                          unsigned short* __restrict__ kwb,
                                                          unsigned short* __restrict__ uwb) {
  const float* src = (blockIdx.y == 0) ? kw : uw;
  unsigned short* dst = (blockIdx.y == 0) ? kwb : uwb;
  size_t i = ((size_t)blockIdx.x * 256 + threadIdx.x) * 8;  // 1,048,576 total
  float4 a = *(const float4*)&src[i];
  float4 b = *(const float4*)&src[i + 4];
  ushort4 ua, ub;
  ua.x = f2bh(a.x); ua.y = f2bh(a.y); ua.z = f2bh(a.z); ua.w = f2bh(a.w);
  ub.x = f2bh(b.x); ub.y = f2bh(b.y); ub.z = f2bh(b.z); ub.w = f2bh(b.w);
  *(ushort4*)&dst[i] = ua;
  *(ushort4*)&dst[i + 4] = ub;
}

// ---------------- weight prep: vw [e][256 f][128 d] -> vwtb bf16 [e][128 d][256 f]
__global__ __launch_bounds__(256) void transpose_vw_kernel(const float* __restrict__ vw,
                                                           unsigned short* __restrict__ vwtb) {
  int e = blockIdx.x, ft = blockIdx.y, dt = blockIdx.z;  // (32, 4, 2)
  int tid = threadIdx.x;
  __shared__ float tile[64][65];
  const float* src = vw + ((size_t)e * 256 + ft * 64) * 128 + dt * 64;
#pragma unroll
  for (int it = 0; it < 4; ++it) {
    int idx = it * 256 + tid;
    int r = idx >> 4, c4 = (idx & 15) * 4;
    float4 v = *(const float4*)&src[(size_t)r * 128 + c4];
    tile[r][c4] = v.x; tile[r][c4 + 1] = v.y; tile[r][c4 + 2] = v.z; tile[r][c4 + 3] = v.w;
  }
  __syncthreads();
  unsigned short* dst = vwtb + ((size_t)e * 128 + dt * 64) * 256 + ft * 64;
#pragma unroll
  for (int it = 0; it < 4; ++it) {
    int idx = it * 256 + tid;
    int dl = idx >> 4, f4 = (idx & 15) * 4;
    ushort4 u;
    u.x = f2bh(tile[f4 + 0][dl]); u.y = f2bh(tile[f4 + 1][dl]);
    u.z = f2bh(tile[f4 + 2][dl]); u.w = f2bh(tile[f4 + 3][dl]);
    *(ushort4*)&dst[(size_t)dl * 256 + f4] = u;
  }
}

// ============ bf16 MFMA GEMM building blocks ============
// ---- fused QKV: A = x [1024 x 2048]; B rows 0..2047 wq, 2048..2559 wk, 2560..3071 wv
__global__ __launch_bounds__(256) void qkv_mfma_kernel(const float* __restrict__ A,
                                                       const float* __restrict__ wq,
                                                       const float* __restrict__ wk,
                                                       const float* __restrict__ wv,
                                                       float* __restrict__ qb,
                                                       float* __restrict__ kb,
                                                       float* __restrict__ vb) {
  int bm = blockIdx.y * 128;
  int bn = blockIdx.x * 128;
  const float* B; float* C; int ldc, cb;
  if (bn < 2048)      { B = wq + (size_t)bn * 2048;          C = qb; ldc = 2048; cb = bn; }
  else if (bn < 2560) { B = wk + (size_t)(bn - 2048) * 2048; C = kb; ldc = 512;  cb = bn - 2048; }
  else                { B = wv + (size_t)(bn - 2560) * 2048; C = vb; ldc = 512;  cb = bn - 2560; }
  int tid = threadIdx.x, wave = tid >> 6, lane = tid & 63;
  int lq = lane & 15, lg4 = lane >> 4;
  int wr = (wave >> 1) * 64, wc = (wave & 1) * 64;
  __shared__ __align__(16) unsigned short Als[128 * 64];
  __shared__ __align__(16) unsigned short Bls[128 * 64];
  f32x4 acc[4][4];
#pragma unroll
  for (int i = 0; i < 4; ++i)
#pragma unroll
    for (int j = 0; j < 4; ++j) acc[i][j] = (f32x4){0.f, 0.f, 0.f, 0.f};
  for (int k0 = 0; k0 < 2048; k0 += 64) {
    __syncthreads();
#pragma unroll
    for (int it = 0; it < 8; ++it) {
      int idx = it * 256 + tid;
      int r = idx >> 4, c4 = (idx & 15) * 4;
      float4 av = *(const float4*)&A[(size_t)(bm + r) * 2048 + k0 + c4];
      ushort4 ua; ua.x = f2bh(av.x); ua.y = f2bh(av.y); ua.z = f2bh(av.z); ua.w = f2bh(av.w);
      *(ushort4*)((char*)Als + ((r * 128 + c4 * 2) ^ ((r & 7) << 4))) = ua;
      float4 bv = *(const float4*)&B[(size_t)r * 2048 + k0 + c4];
      ushort4 ub; ub.x = f2bh(bv.x); ub.y = f2bh(bv.y); ub.z = f2bh(bv.z); ub.w = f2bh(bv.w);
      *(ushort4*)((char*)Bls + ((r * 128 + c4 * 2) ^ ((r & 7) << 4))) = ub;
    }
    __syncthreads();
#pragma unroll
    for (int ks = 0; ks < 2; ++ks) {
      bf16x8 af[4], bfr[4];
#pragma unroll
      for (int mi = 0; mi < 4; ++mi) {
        int row = wr + mi * 16 + lq;
        af[mi] = *(const bf16x8*)((const char*)Als + ((row * 128 + ks * 64 + lg4 * 16) ^ ((row & 7) << 4)));
      }
#pragma unroll
      for (int ni = 0; ni < 4; ++ni) {
        int row = wc + ni * 16 + lq;
        bfr[ni] = *(const bf16x8*)((const char*)Bls + ((row * 128 + ks * 64 + lg4 * 16) ^ ((row & 7) << 4)));
      }
#pragma unroll
      for (int mi = 0; mi < 4; ++mi)
#pragma unroll
        for (int ni = 0; ni < 4; ++ni)
          acc[mi][ni] = __builtin_amdgcn_mfma_f32_16x16x32_bf16(af[mi], bfr[ni], acc[mi][ni], 0, 0, 0);
    }
  }
#pragma unroll
  for (int mi = 0; mi < 4; ++mi)
#pragma unroll
    for (int ni = 0; ni < 4; ++ni) {
      int col = cb + wc + ni * 16 + lq;
#pragma unroll
      for (int reg = 0; reg < 4; ++reg) {
        int m = bm + wr + mi * 16 + lg4 * 4 + reg;
        C[(size_t)m * ldc + col] = acc[mi][ni][reg];
      }
    }
}

// ---- WO GEMM with residual: out[M,N] = attn[M,K] @ wo[N,K]^T + hidden
__global__ __launch_bounds__(256) void wo_mfma_kernel(const float* __restrict__ A,
                                                      const float* __restrict__ Bmat,
                                                      const float* __restrict__ resid,
                                                      float* __restrict__ C) {
  int bm = blockIdx.y * 128;
  int bn = blockIdx.x * 128;
  int tid = threadIdx.x, wave = tid >> 6, lane = tid & 63;
  int lq = lane & 15, lg4 = lane >> 4;
  int wr = (wave >> 1) * 64, wc = (wave & 1) * 64;
  __shared__ __align__(16) unsigned short Als[128 * 64];
  __shared__ __align__(16) unsigned short Bls[128 * 64];
  f32x4 acc[4][4];
#pragma unroll
  for (int i = 0; i < 4; ++i)
#pragma unroll
    for (int j = 0; j < 4; ++j) acc[i][j] = (f32x4){0.f, 0.f, 0.f, 0.f};
  for (int k0 = 0; k0 < 2048; k0 += 64) {
    __syncthreads();
#pragma unroll
    for (int it = 0; it < 8; ++it) {
      int idx = it * 256 + tid;
      int r = idx >> 4, c4 = (idx & 15) * 4;
      float4 av = *(const float4*)&A[(size_t)(bm + r) * 2048 + k0 + c4];
      ushort4 ua; ua.x = f2bh(av.x); ua.y = f2bh(av.y); ua.z = f2bh(av.z); ua.w = f2bh(av.w);
      *(ushort4*)((char*)Als + ((r * 128 + c4 * 2) ^ ((r & 7) << 4))) = ua;
      float4 bv = *(const float4*)&Bmat[(size_t)(bn + r) * 2048 + k0 + c4];
      ushort4 ub; ub.x = f2bh(bv.x); ub.y = f2bh(bv.y); ub.z = f2bh(bv.z); ub.w = f2bh(bv.w);
      *(ushort4*)((char*)Bls + ((r * 128 + c4 * 2) ^ ((r & 7) << 4))) = ub;
    }
    __syncthreads();
#pragma unroll
    for (int ks = 0; ks < 2; ++ks) {
      bf16x8 af[4], bfr[4];
#pragma unroll
      for (int mi = 0; mi < 4; ++mi) {
        int row = wr + mi * 16 + lq;
        af[mi] = *(const bf16x8*)((const char*)Als + ((row * 128 + ks * 64 + lg4 * 16) ^ ((row & 7) << 4)));
      }
#pragma unroll
      for (int ni = 0; ni < 4; ++ni) {
        int row = wc + ni * 16 + lq;
        bfr[ni] = *(const bf16x8*)((const char*)Bls + ((row * 128 + ks * 64 + lg4 * 16) ^ ((row & 7) << 4)));
      }
#pragma unroll
      for (int mi = 0; mi < 4; ++mi)
#pragma unroll
        for (int ni = 0; ni < 4; ++ni)
          acc[mi][ni] = __builtin_amdgcn_mfma_f32_16x16x32_bf16(af[mi], bfr[ni], acc[mi][ni], 0, 0, 0);
    }
  }
#pragma unroll
  for (int mi = 0; mi < 4; ++mi)
#pragma unroll
    for (int ni = 0; ni < 4; ++ni) {
      int col = bn + wc + ni * 16 + lq;
#pragma unroll
      for (int reg = 0; reg < 4; ++reg) {
        int m = bm + wr + mi * 16 + lg4 * 4 + reg;
        C[(size_t)m * 2048 + col] = acc[mi][ni][reg] + resid[(size_t)m * 2048 + col];
      }
    }
}

// ---------------- RoPE (in place on q and k) ----------------
__global__ void rope_kernel(float* __restrict__ qb, float* __restrict__ kb,
                            const float* __restrict__ cosb, const float* __restrict__ sinb) {
  int s = blockIdx.x, tid = threadIdx.x;
  for (int idx = tid; idx < (NH_ + NKV_) * 64; idx += 256) {
    int hh = idx >> 6;
    int d = idx & 63;
    float c0 = cosb[s * HD_ + d], s0 = sinb[s * HD_ + d];
    float c1 = cosb[s * HD_ + d + 64], s1 = sinb[s * HD_ + d + 64];
    float* p;
    if (hh < NH_) p = qb + (size_t)s * 2048 + hh * 128;
    else          p = kb + (size_t)s * 512 + (hh - NH_) * 128;
    float a = p[d], b = p[d + 64];
    p[d] = a * c0 - b * s0;
    p[d + 64] = b * c1 + a * s1;
  }
}

// ---------------- MFMA flash attention (causal GQA) ----------------
__global__ __launch_bounds__(256) void attn_mfma_kernel(const float* __restrict__ qb,
                                                        const float* __restrict__ kb,
                                                        const float* __restrict__ vb,
                                                        float* __restrict__ ob) {
  int n = blockIdx.x, qt = blockIdx.y;
  int g = n >> 2;
  int tid = threadIdx.x;
  int wave = tid >> 6, lane = tid & 63;
  int lq = lane & 15, lg4 = lane >> 4;

  __shared__ __align__(16) unsigned short Kls[64 * 128];
  __shared__ __align__(16) unsigned short Vls[128 * 64];
  __shared__ __align__(16) unsigned short Pls[4][16 * 64];
  __shared__ __align__(16) float corr_ls[4][16];
  __shared__ __align__(16) float lsum_ls[4][16];

  int q0 = qt * 64 + wave * 16;
  bf16x8 qfrag[4];
  {
    const float* qp = qb + (size_t)(q0 + lq) * 2048 + n * 128;
#pragma unroll
    for (int ks = 0; ks < 4; ++ks) {
      float4 a = *(const float4*)&qp[ks * 32 + lg4 * 8];
      float4 b = *(const float4*)&qp[ks * 32 + lg4 * 8 + 4];
      bf16x8 f;
      f[0] = (short)f2bf(a.x); f[1] = (short)f2bf(a.y);
      f[2] = (short)f2bf(a.z); f[3] = (short)f2bf(a.w);
      f[4] = (short)f2bf(b.x); f[5] = (short)f2bf(b.y);
      f[6] = (short)f2bf(b.z); f[7] = (short)f2bf(b.w);
      qfrag[ks] = f;
    }
  }
  f32x4 oacc[8];
#pragma unroll
  for (int i = 0; i < 8; ++i) oacc[i] = (f32x4){0.f, 0.f, 0.f, 0.f};
  float mrow = -1e30f, lrow = 0.f;

  int nt = qt + 1;
  for (int t = 0; t < nt; ++t) {
    int kv0 = t * 64;
    __syncthreads();
#pragma unroll
    for (int it = 0; it < 8; ++it) {
      int idx = it * 256 + tid;
      int r = idx >> 5;
      int c4 = (idx & 31) * 4;
      size_t gbase = (size_t)(kv0 + r) * 512 + g * 128 + c4;
      float4 kv = *(const float4*)&kb[gbase];
      ushort4 u;
      u.x = f2bf(kv.x); u.y = f2bf(kv.y); u.z = f2bf(kv.z); u.w = f2bf(kv.w);
      *(ushort4*)((char*)Kls + ((r * 256 + c4 * 2) ^ ((r & 7) << 4))) = u;
      float4 vv = *(const float4*)&vb[gbase];
      unsigned short vs0 = f2bf(vv.x), vs1 = f2bf(vv.y), vs2 = f2bf(vv.z), vs3 = f2bf(vv.w);
      *(unsigned short*)((char*)Vls + (((c4 + 0) * 128 + r * 2) ^ (((c4 + 0) & 7) << 4))) = vs0;
      *(unsigned short*)((char*)Vls + (((c4 + 1) * 128 + r * 2) ^ (((c4 + 1) & 7) << 4))) = vs1;
      *(unsigned short*)((char*)Vls + (((c4 + 2) * 128 + r * 2) ^ (((c4 + 2) & 7) << 4))) = vs2;
      *(unsigned short*)((char*)Vls + (((c4 + 3) * 128 + r * 2) ^ (((c4 + 3) & 7) << 4))) = vs3;
    }
    __syncthreads();
    f32x4 sacc[4];
#pragma unroll
    for (int i = 0; i < 4; ++i) sacc[i] = (f32x4){0.f, 0.f, 0.f, 0.f};
#pragma unroll
    for (int kt = 0; kt < 4; ++kt) {
      int row = kt * 16 + lq;
#pragma unroll
      for (int ks = 0; ks < 4; ++ks) {
        bf16x8 kf = *(const bf16x8*)((const char*)Kls +
                     ((row * 256 + ks * 64 + lg4 * 16) ^ ((row & 7) << 4)));
        sacc[kt] = __builtin_amdgcn_mfma_f32_16x16x32_bf16(kf, qfrag[ks], sacc[kt], 0, 0, 0);
      }
    }
    int qg = q0 + lq;
    float s[16], p[16];
    float rmax = -1e30f;
#pragma unroll
    for (int kt = 0; kt < 4; ++kt) {
#pragma unroll
      for (int r = 0; r < 4; ++r) {
        int kg = kv0 + kt * 16 + lg4 * 4 + r;
        float v = sacc[kt][r] * SCALE_;
        v = (kg <= qg) ? v : -1e30f;
        s[kt * 4 + r] = v;
        rmax = fmaxf(rmax, v);
      }
    }
    rmax = fmaxf(rmax, __shfl_xor(rmax, 16));
    rmax = fmaxf(rmax, __shfl_xor(rmax, 32));
    float mnew = fmaxf(mrow, rmax);
    float corr = __expf(mrow - mnew);
    float psum = 0.f;
#pragma unroll
    for (int i = 0; i < 16; ++i) { p[i] = __expf(s[i] - mnew); psum += p[i]; }
    psum += __shfl_xor(psum, 16);
    psum += __shfl_xor(psum, 32);
    lrow = lrow * corr + psum;
    mrow = mnew;
    if (lane < 16) corr_ls[wave][lq] = corr;
#pragma unroll
    for (int kt = 0; kt < 4; ++kt) {
      unsigned u0 = (unsigned)f2bf(p[kt * 4 + 0]) | ((unsigned)f2bf(p[kt * 4 + 1]) << 16);
      unsigned u1 = (unsigned)f2bf(p[kt * 4 + 2]) | ((unsigned)f2bf(p[kt * 4 + 3]) << 16);
      int colb = kt * 32 + lg4 * 8;
      *(unsigned*)((char*)&Pls[wave][0] + ((lq * 128 + colb) ^ ((lq & 7) << 4))) = u0;
      *(unsigned*)((char*)&Pls[wave][0] + ((lq * 128 + colb + 4) ^ ((lq & 7) << 4))) = u1;
    }
    f32x4 c4v = *(const f32x4*)&corr_ls[wave][lg4 * 4];
#pragma unroll
    for (int dt = 0; dt < 8; ++dt) {
#pragma unroll
      for (int r = 0; r < 4; ++r) oacc[dt][r] *= c4v[r];
    }
    bf16x8 pfrag[2];
#pragma unroll
    for (int ks2 = 0; ks2 < 2; ++ks2)
      pfrag[ks2] = *(const bf16x8*)((const char*)&Pls[wave][0] +
                    ((lq * 128 + ks2 * 64 + lg4 * 16) ^ ((lq & 7) << 4)));
#pragma unroll
    for (int dt = 0; dt < 8; ++dt) {
      int dr = dt * 16 + lq;
#pragma unroll
      for (int ks2 = 0; ks2 < 2; ++ks2) {
        bf16x8 vf = *(const bf16x8*)((const char*)Vls +
                     ((dr * 128 + ks2 * 64 + lg4 * 16) ^ ((dr & 7) << 4)));
        oacc[dt] = __builtin_amdgcn_mfma_f32_16x16x32_bf16(pfrag[ks2], vf, oacc[dt], 0, 0, 0);
      }
    }
  }
  if (lane < 16) lsum_ls[wave][lq] = lrow;
  f32x4 l4 = *(const f32x4*)&lsum_ls[wave][lg4 * 4];
#pragma unroll
  for (int dt = 0; dt < 8; ++dt) {
#pragma unroll
    for (int r = 0; r < 4; ++r) {
      ob[(size_t)(q0 + lg4 * 4 + r) * 2048 + n * 128 + dt * 16 + lq] = oacc[dt][r] / l4[r];
    }
  }
}

// ---------------- RMSNorm #2 (row norm, per-head norm; fp32 + bf16 outputs) ---
__global__ void rmsnorm2_kernel(const float* __restrict__ hin, const float* __restrict__ ln2w,
                                const float* __restrict__ mhw, float* __restrict__ yout,
                                unsigned short* __restrict__ ybb) {
  int s = blockIdx.x, tid = threadIdx.x;  // 256
  const float* row = hin + (size_t)s * H_;
  __shared__ float y1[H_];
  __shared__ float red[256];
  __shared__ float ph[16][17];
  float ss = 0.f;
  for (int i = tid; i < H_; i += 256) { float v = row[i]; ss += v * v; }
  red[tid] = ss; __syncthreads();
  for (int off = 128; off > 0; off >>= 1) {
    if (tid < off) red[tid] += red[tid + off];
    __syncthreads();
  }
  float rs1 = rsqrtf(red[0] / H_ + EPS_);
  for (int i = tid; i < H_; i += 256) y1[i] = row[i] * rs1 * ln2w[i];
  __syncthreads();
  int n = tid >> 4, j = tid & 15;
  float s2 = 0.f;
  for (int d = j * 8; d < j * 8 + 8; ++d) { float v = y1[n * 128 + d]; s2 += v * v; }
  ph[n][j] = s2; __syncthreads();
  if (j == 0) {
    float t = 0.f;
    for (int q = 0; q < 16; ++q) t += ph[n][q];
    ph[n][16] = rsqrtf(t / HD_ + EPS_);
  }
  __syncthreads();
  for (int i = tid; i < H_; i += 256) {
    int hn = i >> 7;
    float v = y1[i] * ph[hn][16] * mhw[i];
    yout[(size_t)s * H_ + i] = v;
    ybb[(size_t)s * H_ + i] = f2bh(v);
  }
}

// ---------------- router: softmax + top2 + scatter into expert lists ---------
__global__ void route_kernel(const float* __restrict__ yb, const float* __restrict__ rw,
                             int* __restrict__ cnt, int* __restrict__ idxb,
                             float* __restrict__ wtb) {
  int s = blockIdx.x, tid = threadIdx.x;  // 128
  int n = tid >> 3, e = tid & 7;
  const float* yrow = yb + (size_t)s * 2048 + n * 128;
  const float* wrow = rw + (size_t)(n * 8 + e) * 128;
  float lg = 0.f;
  for (int d = 0; d < 128; ++d) lg += yrow[d] * wrow[d];
  float mx = lg;
  for (int off = 1; off < 8; off <<= 1) mx = fmaxf(mx, __shfl_xor(mx, off));
  float p = __expf(lg - mx);
  float sum = p;
  for (int off = 1; off < 8; off <<= 1) sum += __shfl_xor(sum, off);
  float rp = p / sum;
  float v1 = rp; int i1 = e;
  for (int off = 1; off < 8; off <<= 1) {
    float ov = __shfl_xor(v1, off); int oi = __shfl_xor(i1, off);
    if (ov > v1 || (ov == v1 && oi < i1)) { v1 = ov; i1 = oi; }
  }
  float v2 = (e == i1) ? -1e30f : rp; int i2 = e;
  for (int off = 1; off < 8; off <<= 1) {
    float ov = __shfl_xor(v2, off); int oi = __shfl_xor(i2, off);
    if (ov > v2 || (ov == v2 && oi < i2)) { v2 = ov; i2 = oi; }
  }
  if (e == 0) {
    float wsum = v1 + v2;
    int pe1 = n * 8 + i1;
    int pos1 = atomicAdd(&cnt[pe1], 1);
    idxb[pe1 * S_ + pos1] = s; wtb[pe1 * S_ + pos1] = v1 / wsum;
    int pe2 = n * 8 + i2;
    int pos2 = atomicAdd(&cnt[pe2], 1);
    idxb[pe2 * S_ + pos2] = s; wtb[pe2 * S_ + pos2] = v2 / wsum;
  }
}

// ---------------- MoE FFN v2: bf16 weights, fused per-fc pipeline ------------
// block = (pe, 64-token chunk). Per fc (64 f): one barrier pair stages
// KWb+UWb [64][128] and VWtb [128][64]; then per wave: 16 gate + 16 up MFMAs,
// act -> per-wave LDS slice [16][64], 16 down MFMAs (accumulated over fc).
__global__ __launch_bounds__(256) void moe_ffn_mfma_kernel(
    const unsigned short* __restrict__ ybb, const unsigned short* __restrict__ kwb,
    const unsigned short* __restrict__ uwb, const unsigned short* __restrict__ vwtb,
    const int* __restrict__ cnt, const int* __restrict__ idxb,
    const float* __restrict__ wtb, float* __restrict__ out) {
  int pe = blockIdx.x;
  int c = cnt[pe];
  int base = blockIdx.y * 64;
  if (base >= c) return;
  int n = pe >> 3, e = pe & 7, g = n >> 2;
  int eW = g * 8 + e;
  int nr = min(64, c - base);
  int tid = threadIdx.x, wave = tid >> 6, lane = tid & 63;
  int lq = lane & 15, lg4 = lane >> 4;

  __shared__ __align__(16) unsigned short Yls[64 * 128];       // rows 256B, swz
  __shared__ __align__(16) unsigned short WstK[64 * 128];      // rows 256B, swz
  __shared__ __align__(16) unsigned short WstU[64 * 128];      // rows 256B, swz
  __shared__ __align__(16) unsigned short WstV[128 * 64];      // rows 128B, swz
  __shared__ __align__(16) unsigned short Act[4][16 * 64];     // per-wave, rows 128B, swz
  __shared__ int sidx[64];
  __shared__ float swt[64];

  if (tid < 64) {
    sidx[tid] = (tid < nr) ? idxb[pe * S_ + base + tid] : 0;
    swt[tid]  = (tid < nr) ? wtb[pe * S_ + base + tid] : 0.f;
  }
  __syncthreads();
  // stage gathered Y rows [64][128] bf16 (short8 loads)
#pragma unroll
  for (int it = 0; it < 4; ++it) {
    int idx = it * 256 + tid;
    int r = idx >> 4, c8 = (idx & 15) * 8;
    bf16x8 v = {0, 0, 0, 0, 0, 0, 0, 0};
    if (r < nr) v = *(const bf16x8*)&ybb[(size_t)sidx[r] * 2048 + n * 128 + c8];
    *(bf16x8*)((char*)Yls + ((r * 256 + c8 * 2) ^ ((r & 7) << 4))) = v;
  }
  __syncthreads();
  // Y A-fragments in registers for all fc iterations
  bf16x8 yfrag[4];
  {
    int arow = wave * 16 + lq;
#pragma unroll
    for (int ks = 0; ks < 4; ++ks)
      yfrag[ks] = *(const bf16x8*)((const char*)Yls + ((arow * 256 + ks * 64 + lg4 * 16) ^ ((arow & 7) << 4)));
  }
  float wts[4];
#pragma unroll
  for (int reg = 0; reg < 4; ++reg) wts[reg] = swt[wave * 16 + lg4 * 4 + reg];

  f32x4 dacc[8];
#pragma unroll
  for (int i = 0; i < 8; ++i) dacc[i] = (f32x4){0.f, 0.f, 0.f, 0.f};

  for (int fc = 0; fc < 4; ++fc) {
    __syncthreads();
    // stage KWb chunk [64 f][128 k] + UWb chunk (rows 256B)
#pragma unroll
    for (int it = 0; it < 4; ++it) {
      int idx = it * 256 + tid;
      int r = idx >> 4, c8 = (idx & 15) * 8;
      size_t goff = ((size_t)(eW * 256 + fc * 64 + r)) * 128 + c8;
      bf16x8 kv = *(const bf16x8*)&kwb[goff];
      *(bf16x8*)((char*)WstK + ((r * 256 + c8 * 2) ^ ((r & 7) << 4))) = kv;
      bf16x8 uv = *(const bf16x8*)&uwb[goff];
      *(bf16x8*)((char*)WstU + ((r * 256 + c8 * 2) ^ ((r & 7) << 4))) = uv;
    }
    // stage VWtb chunk [128 d][64 f] (rows 128B)
#pragma unroll
    for (int it = 0; it < 4; ++it) {
      int idx = it * 256 + tid;
      int r = idx >> 3, c8 = (idx & 7) * 8;
      bf16x8 vv = *(const bf16x8*)&vwtb[((size_t)(eW * 128 + r)) * 256 + fc * 64 + c8];
      *(bf16x8*)((char*)WstV + ((r * 128 + c8 * 2) ^ ((r & 7) << 4))) = vv;
    }
    __syncthreads();
    // gate/up MFMAs
    f32x4 gacc[4], uacc[4];
#pragma unroll
    for (int i = 0; i < 4; ++i) { gacc[i] = (f32x4){0.f, 0.f, 0.f, 0.f}; uacc[i] = (f32x4){0.f, 0.f, 0.f, 0.f}; }
#pragma unroll
    for (int ks = 0; ks < 4; ++ks) {
#pragma unroll
      for (int nf = 0; nf < 4; ++nf) {
        int brow = nf * 16 + lq;
        bf16x8 bk = *(const bf16x8*)((const char*)WstK + ((brow * 256 + ks * 64 + lg4 * 16) ^ ((brow & 7) << 4)));
        gacc[nf] = __builtin_amdgcn_mfma_f32_16x16x32_bf16(yfrag[ks], bk, gacc[nf], 0, 0, 0);
        bf16x8 bu = *(const bf16x8*)((const char*)WstU + ((brow * 256 + ks * 64 + lg4 * 16) ^ ((brow & 7) << 4)));
        uacc[nf] = __builtin_amdgcn_mfma_f32_16x16x32_bf16(yfrag[ks], bu, uacc[nf], 0, 0, 0);
      }
    }
    // act -> per-wave LDS slice [16 m][64 f]
#pragma unroll
    for (int nf = 0; nf < 4; ++nf) {
#pragma unroll
      for (int reg = 0; reg < 4; ++reg) {
        int m = lg4 * 4 + reg;
        int f = nf * 16 + lq;
        float gg = gacc[nf][reg];
        float uu = uacc[nf][reg];
        float sig = 1.f / (1.f + __expf(-gg));
        float av = gg * sig * uu * wts[reg];
        *(unsigned short*)((char*)&Act[wave][0] + ((m * 128 + f * 2) ^ ((m & 7) << 4))) = f2bh(av);
      }
    }
    // down MFMAs: A = act slice, B = VWt chunk; accumulate over fc
    bf16x8 afrag[2];
#pragma unroll
    for (int ks2 = 0; ks2 < 2; ++ks2)
      afrag[ks2] = *(const bf16x8*)((const char*)&Act[wave][0] + ((lq * 128 + ks2 * 64 + lg4 * 16) ^ ((lq & 7) << 4)));
#pragma unroll
    for (int nd = 0; nd < 8; ++nd) {
      int drow = nd * 16 + lq;
#pragma unroll
      for (int ks2 = 0; ks2 < 2; ++ks2) {
        bf16x8 b = *(const bf16x8*)((const char*)WstV + ((drow * 128 + ks2 * 64 + lg4 * 16) ^ ((drow & 7) << 4)));
        dacc[nd] = __builtin_amdgcn_mfma_f32_16x16x32_bf16(afrag[ks2], b, dacc[nd], 0, 0, 0);
      }
    }
  }
  // epilogue: atomic accumulate into out
#pragma unroll
  for (int nd = 0; nd < 8; ++nd) {
    int d = nd * 16 + lq;
#pragma unroll
    for (int reg = 0; reg < 4; ++reg) {
      int mloc = wave * 16 + lg4 * 4 + reg;
      if (mloc < nr) {
        atomicAdd(&out[(size_t)sidx[mloc] * 2048 + n * 128 + d], dacc[nd][reg]);
      }
    }
  }
}

extern "C" void kernel_launch(void* const* d_in, const int* in_sizes, int n_in,
                              void* d_out, int out_size, void* d_ws, size_t ws_size,
                              hipStream_t stream) {
  const float* hidden = (const float*)d_in[0];
  const float* cosb   = (const float*)d_in[1];
  const float* sinb   = (const float*)d_in[2];
  // d_in[3] = attn_mask (unused; causal handled analytically)
  const float* ln1w   = (const float*)d_in[4];
  const float* ln2w   = (const float*)d_in[5];
  const float* wq     = (const float*)d_in[6];
  const float* wk     = (const float*)d_in[7];
  const float* wv     = (const float*)d_in[8];
  const float* wo     = (const float*)d_in[9];
  const float* mhw    = (const float*)d_in[10];
  const float* rw     = (const float*)d_in[11];
  const float* kww    = (const float*)d_in[12];
  const float* uww    = (const float*)d_in[13];
  const float* vww    = (const float*)d_in[14];
  float* out = (float*)d_out;

  float* ws = (float*)d_ws;
  float* x     = ws;                        // 1024x2048 f32
  float* qb    = x + 2097152;
  float* kb    = qb + 2097152;
  float* vb    = kb + 524288;
  float* attnb = vb + 524288;
  float* yb    = attnb + 2097152;
  int*   cntb  = (int*)(yb + 2097152);      // 128
  int*   idxb  = cntb + 128;                // 128K
  float* wtb   = (float*)(idxb + 131072);   // 128K
  unsigned short* ybb  = (unsigned short*)(wtb + 131072);  // 1024x2048 bf16
  unsigned short* kwb  = ybb + 2097152;     // 32x256x128 bf16
  unsigned short* uwb  = kwb + 1048576;
  unsigned short* vwtb = uwb + 1048576;     // 32x128x256 bf16 (transposed)

  hipMemsetAsync(cntb, 0, 128 * sizeof(int), stream);

  convert_kuw_kernel<<<dim3(512, 2), 256, 0, stream>>>(kww, uww, kwb, uwb);
  transpose_vw_kernel<<<dim3(32, 4, 2), 256, 0, stream>>>(vww, vwtb);

  rmsnorm1_kernel<<<S_, 256, 0, stream>>>(hidden, ln1w, x);

  qkv_mfma_kernel<<<dim3(24, 8), 256, 0, stream>>>(x, wq, wk, wv, qb, kb, vb);

  rope_kernel<<<S_, 256, 0, stream>>>(qb, kb, cosb, sinb);

  attn_mfma_kernel<<<dim3(NH_, S_ / 64), 256, 0, stream>>>(qb, kb, vb, attnb);

  wo_mfma_kernel<<<dim3(16, 8), 256, 0, stream>>>(attnb, wo, hidden, out);

  rmsnorm2_kernel<<<S_, 256, 0, stream>>>(out, ln2w, mhw, yb, ybb);

  route_kernel<<<S_, 128, 0, stream>>>(yb, rw, cntb, idxb, wtb);

  moe_ffn_mfma_kernel<<<dim3(128, 16), 256, 0, stream>>>(ybb, kwb, uwb, vwtb, cntb, idxb, wtb, out);
}

// Round 6
// 378.269 us; speedup vs baseline: 6.6676x; 1.1571x over previous
//
#include <hip/hip_runtime.h>
#include <hip/hip_bf16.h>

#define S_ 1024
#define H_ 2048
#define NH_ 16
#define NKV_ 4
#define HD_ 128
#define E_ 8
#define F_ 256
#define EPS_ 1e-6f
#define SCALE_ 0.08838834764831845f  // 128^-0.5

typedef __attribute__((ext_vector_type(8))) short bf16x8;
typedef __attribute__((ext_vector_type(4))) float f32x4;

static __device__ __forceinline__ unsigned short f2bf(float x) {
  unsigned u = __float_as_uint(x);
  unsigned r = (u + 0x7FFFu + ((u >> 16) & 1u)) >> 16;
  return (unsigned short)r;
}
static __device__ __forceinline__ unsigned short f2bh(float x) {
  __hip_bfloat16 b = __float2bfloat16(x);
  return *reinterpret_cast<unsigned short*>(&b);
}

// ---------------- RMSNorm #1 -> bf16 ----------------
__global__ void rmsnorm1_kernel(const float* __restrict__ in, const float* __restrict__ w,
                                unsigned short* __restrict__ outb) {
  int s = blockIdx.x, tid = threadIdx.x;
  const float* row = in + s * H_;
  __shared__ float red[256];
  float ss = 0.f;
  for (int i = tid; i < H_; i += 256) { float v = row[i]; ss += v * v; }
  red[tid] = ss; __syncthreads();
  for (int off = 128; off > 0; off >>= 1) {
    if (tid < off) red[tid] += red[tid + off];
    __syncthreads();
  }
  float rs = rsqrtf(red[0] / H_ + EPS_);
  for (int i = tid; i < H_; i += 256) outb[(size_t)s * H_ + i] = f2bh(row[i] * rs * w[i]);
}

// ---------------- weight prep: kw/uw fp32 -> bf16 ----------------
__global__ __launch_bounds__(256) void convert_kuw_kernel(const float* __restrict__ kw,
                                                          const float* __restrict__ uw,
                                                          unsigned short* __restrict__ kwb,
                                                          unsigned short* __restrict__ uwb) {
  const float* src = (blockIdx.y == 0) ? kw : uw;
  unsigned short* dst = (blockIdx.y == 0) ? kwb : uwb;
  size_t i = ((size_t)blockIdx.x * 256 + threadIdx.x) * 8;
  float4 a = *(const float4*)&src[i];
  float4 b = *(const float4*)&src[i + 4];
  ushort4 ua, ub;
  ua.x = f2bh(a.x); ua.y = f2bh(a.y); ua.z = f2bh(a.z); ua.w = f2bh(a.w);
  ub.x = f2bh(b.x); ub.y = f2bh(b.y); ub.z = f2bh(b.z); ub.w = f2bh(b.w);
  *(ushort4*)&dst[i] = ua;
  *(ushort4*)&dst[i + 4] = ub;
}

// ---------------- weight prep: vw [e][256 f][128 d] -> vwtb bf16 [e][128 d][256 f]
__global__ __launch_bounds__(256) void transpose_vw_kernel(const float* __restrict__ vw,
                                                           unsigned short* __restrict__ vwtb) {
  int e = blockIdx.x, ft = blockIdx.y, dt = blockIdx.z;  // (32, 4, 2)
  int tid = threadIdx.x;
  __shared__ float tile[64][65];
  const float* src = vw + ((size_t)e * 256 + ft * 64) * 128 + dt * 64;
#pragma unroll
  for (int it = 0; it < 4; ++it) {
    int idx = it * 256 + tid;
    int r = idx >> 4, c4 = (idx & 15) * 4;
    float4 v = *(const float4*)&src[(size_t)r * 128 + c4];
    tile[r][c4] = v.x; tile[r][c4 + 1] = v.y; tile[r][c4 + 2] = v.z; tile[r][c4 + 3] = v.w;
  }
  __syncthreads();
  unsigned short* dst = vwtb + ((size_t)e * 128 + dt * 64) * 256 + ft * 64;
#pragma unroll
  for (int it = 0; it < 4; ++it) {
    int idx = it * 256 + tid;
    int dl = idx >> 4, f4 = (idx & 15) * 4;
    ushort4 u;
    u.x = f2bh(tile[f4 + 0][dl]); u.y = f2bh(tile[f4 + 1][dl]);
    u.z = f2bh(tile[f4 + 2][dl]); u.w = f2bh(tile[f4 + 3][dl]);
    *(ushort4*)&dst[(size_t)dl * 256 + f4] = u;
  }
}

// ============ pipelined bf16 MFMA GEMM (64x128 tile, BK=64, dbuf LDS) ============
// A bf16 [M][K]; B fp32 [N][K] (cvt in staging). 4 waves, each 32x64.
// ---- fused QKV
__global__ __launch_bounds__(256) void qkv_mfma_kernel(const unsigned short* __restrict__ xb,
                                                       const float* __restrict__ wq,
                                                       const float* __restrict__ wk,
                                                       const float* __restrict__ wv,
                                                       float* __restrict__ qb,
                                                       float* __restrict__ kb,
                                                       unsigned short* __restrict__ vbb) {
  int bid = blockIdx.x;                       // 384
  int swz = (bid & 7) * 48 + (bid >> 3);      // bijective (384 % 8 == 0)
  int bm = (swz / 24) * 64;
  int bn = (swz % 24) * 128;
  const float* B; float* C = nullptr; unsigned short* Cb = nullptr; int ldc, cb;
  if (bn < 2048)      { B = wq + (size_t)bn * 2048;          C = qb; ldc = 2048; cb = bn; }
  else if (bn < 2560) { B = wk + (size_t)(bn - 2048) * 2048; C = kb; ldc = 512;  cb = bn - 2048; }
  else                { B = wv + (size_t)(bn - 2560) * 2048; Cb = vbb; ldc = 512; cb = bn - 2560; }
  int tid = threadIdx.x, wave = tid >> 6, lane = tid & 63;
  int lq = lane & 15, lg4 = lane >> 4;
  int wr = (wave >> 1) * 32, wc = (wave & 1) * 64;
  __shared__ __align__(16) unsigned short Als[2][64 * 64];
  __shared__ __align__(16) unsigned short Bls[2][128 * 64];
  f32x4 acc[2][4];
#pragma unroll
  for (int i = 0; i < 2; ++i)
#pragma unroll
    for (int j = 0; j < 4; ++j) acc[i][j] = (f32x4){0.f, 0.f, 0.f, 0.f};

  int ar = (tid >> 3), ac8 = (tid & 7) * 8;           // A: it in {0,1}: row ar + it*32
  int br = (tid >> 4), bc4 = (tid & 15) * 4;          // B: it in {0..7}: row br + it*16
  bf16x8 areg[2];
  float4 breg[8];

  auto LOAD = [&](int k0) {
#pragma unroll
    for (int it = 0; it < 2; ++it)
      areg[it] = *(const bf16x8*)&xb[(size_t)(bm + ar + it * 32) * 2048 + k0 + ac8];
#pragma unroll
    for (int it = 0; it < 8; ++it)
      breg[it] = *(const float4*)&B[(size_t)(br + it * 16) * 2048 + k0 + bc4];
  };
  auto STORE = [&](int buf) {
#pragma unroll
    for (int it = 0; it < 2; ++it) {
      int r = ar + it * 32;
      *(bf16x8*)((char*)&Als[buf][0] + ((r * 128 + ac8 * 2) ^ ((r & 7) << 4))) = areg[it];
    }
#pragma unroll
    for (int it = 0; it < 8; ++it) {
      int r = br + it * 16;
      ushort4 u;
      u.x = f2bh(breg[it].x); u.y = f2bh(breg[it].y);
      u.z = f2bh(breg[it].z); u.w = f2bh(breg[it].w);
      *(ushort4*)((char*)&Bls[buf][0] + ((r * 128 + bc4 * 2) ^ ((r & 7) << 4))) = u;
    }
  };

  LOAD(0); STORE(0); __syncthreads();
  int cur = 0;
  for (int t = 0; t < 32; ++t) {
    if (t < 31) LOAD((t + 1) * 64);
#pragma unroll
    for (int ks = 0; ks < 2; ++ks) {
      bf16x8 af[2], bfr[4];
#pragma unroll
      for (int mi = 0; mi < 2; ++mi) {
        int row = wr + mi * 16 + lq;
        af[mi] = *(const bf16x8*)((const char*)&Als[cur][0] + ((row * 128 + ks * 64 + lg4 * 16) ^ ((row & 7) << 4)));
      }
#pragma unroll
      for (int ni = 0; ni < 4; ++ni) {
        int row = wc + ni * 16 + lq;
        bfr[ni] = *(const bf16x8*)((const char*)&Bls[cur][0] + ((row * 128 + ks * 64 + lg4 * 16) ^ ((row & 7) << 4)));
      }
#pragma unroll
      for (int mi = 0; mi < 2; ++mi)
#pragma unroll
        for (int ni = 0; ni < 4; ++ni)
          acc[mi][ni] = __builtin_amdgcn_mfma_f32_16x16x32_bf16(af[mi], bfr[ni], acc[mi][ni], 0, 0, 0);
    }
    if (t < 31) STORE(cur ^ 1);
    __syncthreads();
    cur ^= 1;
  }
#pragma unroll
  for (int mi = 0; mi < 2; ++mi)
#pragma unroll
    for (int ni = 0; ni < 4; ++ni) {
      int col = cb + wc + ni * 16 + lq;
#pragma unroll
      for (int reg = 0; reg < 4; ++reg) {
        int m = bm + wr + mi * 16 + lg4 * 4 + reg;
        if (C) C[(size_t)m * ldc + col] = acc[mi][ni][reg];
        else   Cb[(size_t)m * ldc + col] = f2bh(acc[mi][ni][reg]);
      }
    }
}

// ---- WO GEMM with residual: out = attnbb(bf16) @ wo(f32)^T + hidden
__global__ __launch_bounds__(256) void wo_mfma_kernel(const unsigned short* __restrict__ A,
                                                      const float* __restrict__ Bmat,
                                                      const float* __restrict__ resid,
                                                      float* __restrict__ C) {
  int bid = blockIdx.x;                       // 256
  int swz = (bid & 7) * 32 + (bid >> 3);
  int bm = (swz / 16) * 64;
  int bn = (swz % 16) * 128;
  int tid = threadIdx.x, wave = tid >> 6, lane = tid & 63;
  int lq = lane & 15, lg4 = lane >> 4;
  int wr = (wave >> 1) * 32, wc = (wave & 1) * 64;
  __shared__ __align__(16) unsigned short Als[2][64 * 64];
  __shared__ __align__(16) unsigned short Bls[2][128 * 64];
  f32x4 acc[2][4];
#pragma unroll
  for (int i = 0; i < 2; ++i)
#pragma unroll
    for (int j = 0; j < 4; ++j) acc[i][j] = (f32x4){0.f, 0.f, 0.f, 0.f};

  int ar = (tid >> 3), ac8 = (tid & 7) * 8;
  int br = (tid >> 4), bc4 = (tid & 15) * 4;
  bf16x8 areg[2];
  float4 breg[8];

  auto LOAD = [&](int k0) {
#pragma unroll
    for (int it = 0; it < 2; ++it)
      areg[it] = *(const bf16x8*)&A[(size_t)(bm + ar + it * 32) * 2048 + k0 + ac8];
#pragma unroll
    for (int it = 0; it < 8; ++it)
      breg[it] = *(const float4*)&Bmat[(size_t)(bn + br + it * 16) * 2048 + k0 + bc4];
  };
  auto STORE = [&](int buf) {
#pragma unroll
    for (int it = 0; it < 2; ++it) {
      int r = ar + it * 32;
      *(bf16x8*)((char*)&Als[buf][0] + ((r * 128 + ac8 * 2) ^ ((r & 7) << 4))) = areg[it];
    }
#pragma unroll
    for (int it = 0; it < 8; ++it) {
      int r = br + it * 16;
      ushort4 u;
      u.x = f2bh(breg[it].x); u.y = f2bh(breg[it].y);
      u.z = f2bh(breg[it].z); u.w = f2bh(breg[it].w);
      *(ushort4*)((char*)&Bls[buf][0] + ((r * 128 + bc4 * 2) ^ ((r & 7) << 4))) = u;
    }
  };

  LOAD(0); STORE(0); __syncthreads();
  int cur = 0;
  for (int t = 0; t < 32; ++t) {
    if (t < 31) LOAD((t + 1) * 64);
#pragma unroll
    for (int ks = 0; ks < 2; ++ks) {
      bf16x8 af[2], bfr[4];
#pragma unroll
      for (int mi = 0; mi < 2; ++mi) {
        int row = wr + mi * 16 + lq;
        af[mi] = *(const bf16x8*)((const char*)&Als[cur][0] + ((row * 128 + ks * 64 + lg4 * 16) ^ ((row & 7) << 4)));
      }
#pragma unroll
      for (int ni = 0; ni < 4; ++ni) {
        int row = wc + ni * 16 + lq;
        bfr[ni] = *(const bf16x8*)((const char*)&Bls[cur][0] + ((row * 128 + ks * 64 + lg4 * 16) ^ ((row & 7) << 4)));
      }
#pragma unroll
      for (int mi = 0; mi < 2; ++mi)
#pragma unroll
        for (int ni = 0; ni < 4; ++ni)
          acc[mi][ni] = __builtin_amdgcn_mfma_f32_16x16x32_bf16(af[mi], bfr[ni], acc[mi][ni], 0, 0, 0);
    }
    if (t < 31) STORE(cur ^ 1);
    __syncthreads();
    cur ^= 1;
  }
#pragma unroll
  for (int mi = 0; mi < 2; ++mi)
#pragma unroll
    for (int ni = 0; ni < 4; ++ni) {
      int col = bn + wc + ni * 16 + lq;
#pragma unroll
      for (int reg = 0; reg < 4; ++reg) {
        int m = bm + wr + mi * 16 + lg4 * 4 + reg;
        C[(size_t)m * 2048 + col] = acc[mi][ni][reg] + resid[(size_t)m * 2048 + col];
      }
    }
}

// ---------------- RoPE: fp32 q/k -> rotated bf16 copies ----------------
__global__ void rope_kernel(const float* __restrict__ qb, const float* __restrict__ kb,
                            const float* __restrict__ cosb, const float* __restrict__ sinb,
                            unsigned short* __restrict__ qbb, unsigned short* __restrict__ kbb) {
  int s = blockIdx.x, tid = threadIdx.x;
  for (int idx = tid; idx < (NH_ + NKV_) * 64; idx += 256) {
    int hh = idx >> 6;
    int d = idx & 63;
    float c0 = cosb[s * HD_ + d], s0 = sinb[s * HD_ + d];
    float c1 = cosb[s * HD_ + d + 64], s1 = sinb[s * HD_ + d + 64];
    const float* src; unsigned short* dst;
    if (hh < NH_) { src = qb + (size_t)s * 2048 + hh * 128; dst = qbb + (size_t)s * 2048 + hh * 128; }
    else          { src = kb + (size_t)s * 512 + (hh - NH_) * 128; dst = kbb + (size_t)s * 512 + (hh - NH_) * 128; }
    float a = src[d], b = src[d + 64];
    dst[d] = f2bh(a * c0 - b * s0);
    dst[d + 64] = f2bh(b * c1 + a * s1);
  }
}

// ---------------- MFMA flash attention (causal GQA), all-bf16 I/O ----------------
__global__ __launch_bounds__(256) void attn_mfma_kernel(const unsigned short* __restrict__ qbb,
                                                        const unsigned short* __restrict__ kbb,
                                                        const unsigned short* __restrict__ vbb,
                                                        unsigned short* __restrict__ ob) {
  int n = blockIdx.x, qt = blockIdx.y;
  int g = n >> 2;
  int tid = threadIdx.x;
  int wave = tid >> 6, lane = tid & 63;
  int lq = lane & 15, lg4 = lane >> 4;

  __shared__ __align__(16) unsigned short Kls[64 * 128];
  __shared__ __align__(16) unsigned short Vls[128 * 64];
  __shared__ __align__(16) unsigned short Pls[4][16 * 64];
  __shared__ __align__(16) float corr_ls[4][16];
  __shared__ __align__(16) float lsum_ls[4][16];

  int q0 = qt * 64 + wave * 16;
  bf16x8 qfrag[4];
  {
    const unsigned short* qp = qbb + (size_t)(q0 + lq) * 2048 + n * 128;
#pragma unroll
    for (int ks = 0; ks < 4; ++ks)
      qfrag[ks] = *(const bf16x8*)&qp[ks * 32 + lg4 * 8];
  }
  f32x4 oacc[8];
#pragma unroll
  for (int i = 0; i < 8; ++i) oacc[i] = (f32x4){0.f, 0.f, 0.f, 0.f};
  float mrow = -1e30f, lrow = 0.f;

  int nt = qt + 1;
  for (int t = 0; t < nt; ++t) {
    int kv0 = t * 64;
    __syncthreads();
#pragma unroll
    for (int it = 0; it < 4; ++it) {
      int idx = it * 256 + tid;
      int r = idx >> 4, c8 = (idx & 15) * 8;
      size_t gbase = (size_t)(kv0 + r) * 512 + g * 128 + c8;
      bf16x8 kv = *(const bf16x8*)&kbb[gbase];
      *(bf16x8*)((char*)Kls + ((r * 256 + c8 * 2) ^ ((r & 7) << 4))) = kv;
      bf16x8 vv = *(const bf16x8*)&vbb[gbase];
#pragma unroll
      for (int j = 0; j < 8; ++j) {
        int d = c8 + j;
        *(unsigned short*)((char*)Vls + ((d * 128 + r * 2) ^ ((j) << 4))) = (unsigned short)vv[j];
      }
    }
    __syncthreads();
    f32x4 sacc[4];
#pragma unroll
    for (int i = 0; i < 4; ++i) sacc[i] = (f32x4){0.f, 0.f, 0.f, 0.f};
#pragma unroll
    for (int kt = 0; kt < 4; ++kt) {
      int row = kt * 16 + lq;
#pragma unroll
      for (int ks = 0; ks < 4; ++ks) {
        bf16x8 kf = *(const bf16x8*)((const char*)Kls +
                     ((row * 256 + ks * 64 + lg4 * 16) ^ ((row & 7) << 4)));
        sacc[kt] = __builtin_amdgcn_mfma_f32_16x16x32_bf16(kf, qfrag[ks], sacc[kt], 0, 0, 0);
      }
    }
    int qg = q0 + lq;
    float s[16], p[16];
    float rmax = -1e30f;
#pragma unroll
    for (int kt = 0; kt < 4; ++kt) {
#pragma unroll
      for (int r = 0; r < 4; ++r) {
        int kg = kv0 + kt * 16 + lg4 * 4 + r;
        float v = sacc[kt][r] * SCALE_;
        v = (kg <= qg) ? v : -1e30f;
        s[kt * 4 + r] = v;
        rmax = fmaxf(rmax, v);
      }
    }
    rmax = fmaxf(rmax, __shfl_xor(rmax, 16));
    rmax = fmaxf(rmax, __shfl_xor(rmax, 32));
    float mnew = fmaxf(mrow, rmax);
    float corr = __expf(mrow - mnew);
    float psum = 0.f;
#pragma unroll
    for (int i = 0; i < 16; ++i) { p[i] = __expf(s[i] - mnew); psum += p[i]; }
    psum += __shfl_xor(psum, 16);
    psum += __shfl_xor(psum, 32);
    lrow = lrow * corr + psum;
    mrow = mnew;
    if (lane < 16) corr_ls[wave][lq] = corr;
#pragma unroll
    for (int kt = 0; kt < 4; ++kt) {
      unsigned u0 = (unsigned)f2bf(p[kt * 4 + 0]) | ((unsigned)f2bf(p[kt * 4 + 1]) << 16);
      unsigned u1 = (unsigned)f2bf(p[kt * 4 + 2]) | ((unsigned)f2bf(p[kt * 4 + 3]) << 16);
      int colb = kt * 32 + lg4 * 8;
      *(unsigned*)((char*)&Pls[wave][0] + ((lq * 128 + colb) ^ ((lq & 7) << 4))) = u0;
      *(unsigned*)((char*)&Pls[wave][0] + ((lq * 128 + colb + 4) ^ ((lq & 7) << 4))) = u1;
    }
    f32x4 c4v = *(const f32x4*)&corr_ls[wave][lg4 * 4];
#pragma unroll
    for (int dt = 0; dt < 8; ++dt) {
#pragma unroll
      for (int r = 0; r < 4; ++r) oacc[dt][r] *= c4v[r];
    }
    bf16x8 pfrag[2];
#pragma unroll
    for (int ks2 = 0; ks2 < 2; ++ks2)
      pfrag[ks2] = *(const bf16x8*)((const char*)&Pls[wave][0] +
                    ((lq * 128 + ks2 * 64 + lg4 * 16) ^ ((lq & 7) << 4)));
#pragma unroll
    for (int dt = 0; dt < 8; ++dt) {
      int dr = dt * 16 + lq;
#pragma unroll
      for (int ks2 = 0; ks2 < 2; ++ks2) {
        bf16x8 vf = *(const bf16x8*)((const char*)Vls +
                     ((dr * 128 + ks2 * 64 + lg4 * 16) ^ ((dr & 7) << 4)));
        oacc[dt] = __builtin_amdgcn_mfma_f32_16x16x32_bf16(pfrag[ks2], vf, oacc[dt], 0, 0, 0);
      }
    }
  }
  if (lane < 16) lsum_ls[wave][lq] = lrow;
  f32x4 l4 = *(const f32x4*)&lsum_ls[wave][lg4 * 4];
#pragma unroll
  for (int dt = 0; dt < 8; ++dt) {
#pragma unroll
    for (int r = 0; r < 4; ++r) {
      ob[(size_t)(q0 + lg4 * 4 + r) * 2048 + n * 128 + dt * 16 + lq] = f2bh(oacc[dt][r] / l4[r]);
    }
  }
}

// ---------------- RMSNorm #2 (row norm, per-head norm; fp32 + bf16 outputs) ---
__global__ void rmsnorm2_kernel(const float* __restrict__ hin, const float* __restrict__ ln2w,
                                const float* __restrict__ mhw, float* __restrict__ yout,
                                unsigned short* __restrict__ ybb) {
  int s = blockIdx.x, tid = threadIdx.x;  // 256
  const float* row = hin + (size_t)s * H_;
  __shared__ float y1[H_];
  __shared__ float red[256];
  __shared__ float ph[16][17];
  float ss = 0.f;
  for (int i = tid; i < H_; i += 256) { float v = row[i]; ss += v * v; }
  red[tid] = ss; __syncthreads();
  for (int off = 128; off > 0; off >>= 1) {
    if (tid < off) red[tid] += red[tid + off];
    __syncthreads();
  }
  float rs1 = rsqrtf(red[0] / H_ + EPS_);
  for (int i = tid; i < H_; i += 256) y1[i] = row[i] * rs1 * ln2w[i];
  __syncthreads();
  int n = tid >> 4, j = tid & 15;
  float s2 = 0.f;
  for (int d = j * 8; d < j * 8 + 8; ++d) { float v = y1[n * 128 + d]; s2 += v * v; }
  ph[n][j] = s2; __syncthreads();
  if (j == 0) {
    float t = 0.f;
    for (int q = 0; q < 16; ++q) t += ph[n][q];
    ph[n][16] = rsqrtf(t / HD_ + EPS_);
  }
  __syncthreads();
  for (int i = tid; i < H_; i += 256) {
    int hn = i >> 7;
    float v = y1[i] * ph[hn][16] * mhw[i];
    yout[(size_t)s * H_ + i] = v;
    ybb[(size_t)s * H_ + i] = f2bh(v);
  }
}

// ---------------- router: softmax + top2 + scatter into expert lists ---------
__global__ void route_kernel(const float* __restrict__ yb, const float* __restrict__ rw,
                             int* __restrict__ cnt, int* __restrict__ idxb,
                             float* __restrict__ wtb) {
  int s = blockIdx.x, tid = threadIdx.x;  // 128
  int n = tid >> 3, e = tid & 7;
  const float* yrow = yb + (size_t)s * 2048 + n * 128;
  const float* wrow = rw + (size_t)(n * 8 + e) * 128;
  float lg = 0.f;
  for (int d = 0; d < 128; ++d) lg += yrow[d] * wrow[d];
  float mx = lg;
  for (int off = 1; off < 8; off <<= 1) mx = fmaxf(mx, __shfl_xor(mx, off));
  float p = __expf(lg - mx);
  float sum = p;
  for (int off = 1; off < 8; off <<= 1) sum += __shfl_xor(sum, off);
  float rp = p / sum;
  float v1 = rp; int i1 = e;
  for (int off = 1; off < 8; off <<= 1) {
    float ov = __shfl_xor(v1, off); int oi = __shfl_xor(i1, off);
    if (ov > v1 || (ov == v1 && oi < i1)) { v1 = ov; i1 = oi; }
  }
  float v2 = (e == i1) ? -1e30f : rp; int i2 = e;
  for (int off = 1; off < 8; off <<= 1) {
    float ov = __shfl_xor(v2, off); int oi = __shfl_xor(i2, off);
    if (ov > v2 || (ov == v2 && oi < i2)) { v2 = ov; i2 = oi; }
  }
  if (e == 0) {
    float wsum = v1 + v2;
    int pe1 = n * 8 + i1;
    int pos1 = atomicAdd(&cnt[pe1], 1);
    idxb[pe1 * S_ + pos1] = s; wtb[pe1 * S_ + pos1] = v1 / wsum;
    int pe2 = n * 8 + i2;
    int pos2 = atomicAdd(&cnt[pe2], 1);
    idxb[pe2 * S_ + pos2] = s; wtb[pe2 * S_ + pos2] = v2 / wsum;
  }
}

// ---------------- MoE FFN: bf16 weights, fused per-fc pipeline ------------
__global__ __launch_bounds__(256) void moe_ffn_mfma_kernel(
    const unsigned short* __restrict__ ybb, const unsigned short* __restrict__ kwb,
    const unsigned short* __restrict__ uwb, const unsigned short* __restrict__ vwtb,
    const int* __restrict__ cnt, const int* __restrict__ idxb,
    const float* __restrict__ wtb, float* __restrict__ out) {
  int pe = blockIdx.x;
  int c = cnt[pe];
  int base = blockIdx.y * 64;
  if (base >= c) return;
  int n = pe >> 3, e = pe & 7, g = n >> 2;
  int eW = g * 8 + e;
  int nr = min(64, c - base);
  int tid = threadIdx.x, wave = tid >> 6, lane = tid & 63;
  int lq = lane & 15, lg4 = lane >> 4;

  __shared__ __align__(16) unsigned short Yls[64 * 128];
  __shared__ __align__(16) unsigned short WstK[64 * 128];
  __shared__ __align__(16) unsigned short WstU[64 * 128];
  __shared__ __align__(16) unsigned short WstV[128 * 64];
  __shared__ __align__(16) unsigned short Act[4][16 * 64];
  __shared__ int sidx[64];
  __shared__ float swt[64];

  if (tid < 64) {
    sidx[tid] = (tid < nr) ? idxb[pe * S_ + base + tid] : 0;
    swt[tid]  = (tid < nr) ? wtb[pe * S_ + base + tid] : 0.f;
  }
  __syncthreads();
#pragma unroll
  for (int it = 0; it < 4; ++it) {
    int idx = it * 256 + tid;
    int r = idx >> 4, c8 = (idx & 15) * 8;
    bf16x8 v = {0, 0, 0, 0, 0, 0, 0, 0};
    if (r < nr) v = *(const bf16x8*)&ybb[(size_t)sidx[r] * 2048 + n * 128 + c8];
    *(bf16x8*)((char*)Yls + ((r * 256 + c8 * 2) ^ ((r & 7) << 4))) = v;
  }
  __syncthreads();
  bf16x8 yfrag[4];
  {
    int arow = wave * 16 + lq;
#pragma unroll
    for (int ks = 0; ks < 4; ++ks)
      yfrag[ks] = *(const bf16x8*)((const char*)Yls + ((arow * 256 + ks * 64 + lg4 * 16) ^ ((arow & 7) << 4)));
  }
  float wts[4];
#pragma unroll
  for (int reg = 0; reg < 4; ++reg) wts[reg] = swt[wave * 16 + lg4 * 4 + reg];

  f32x4 dacc[8];
#pragma unroll
  for (int i = 0; i < 8; ++i) dacc[i] = (f32x4){0.f, 0.f, 0.f, 0.f};

  for (int fc = 0; fc < 4; ++fc) {
    __syncthreads();
#pragma unroll
    for (int it = 0; it < 4; ++it) {
      int idx = it * 256 + tid;
      int r = idx >> 4, c8 = (idx & 15) * 8;
      size_t goff = ((size_t)(eW * 256 + fc * 64 + r)) * 128 + c8;
      bf16x8 kv = *(const bf16x8*)&kwb[goff];
      *(bf16x8*)((char*)WstK + ((r * 256 + c8 * 2) ^ ((r & 7) << 4))) = kv;
      bf16x8 uv = *(const bf16x8*)&uwb[goff];
      *(bf16x8*)((char*)WstU + ((r * 256 + c8 * 2) ^ ((r & 7) << 4))) = uv;
    }
#pragma unroll
    for (int it = 0; it < 4; ++it) {
      int idx = it * 256 + tid;
      int r = idx >> 3, c8 = (idx & 7) * 8;
      bf16x8 vv = *(const bf16x8*)&vwtb[((size_t)(eW * 128 + r)) * 256 + fc * 64 + c8];
      *(bf16x8*)((char*)WstV + ((r * 128 + c8 * 2) ^ ((r & 7) << 4))) = vv;
    }
    __syncthreads();
    f32x4 gacc[4], uacc[4];
#pragma unroll
    for (int i = 0; i < 4; ++i) { gacc[i] = (f32x4){0.f, 0.f, 0.f, 0.f}; uacc[i] = (f32x4){0.f, 0.f, 0.f, 0.f}; }
#pragma unroll
    for (int ks = 0; ks < 4; ++ks) {
#pragma unroll
      for (int nf = 0; nf < 4; ++nf) {
        int brow = nf * 16 + lq;
        bf16x8 bk = *(const bf16x8*)((const char*)WstK + ((brow * 256 + ks * 64 + lg4 * 16) ^ ((brow & 7) << 4)));
        gacc[nf] = __builtin_amdgcn_mfma_f32_16x16x32_bf16(yfrag[ks], bk, gacc[nf], 0, 0, 0);
        bf16x8 bu = *(const bf16x8*)((const char*)WstU + ((brow * 256 + ks * 64 + lg4 * 16) ^ ((brow & 7) << 4)));
        uacc[nf] = __builtin_amdgcn_mfma_f32_16x16x32_bf16(yfrag[ks], bu, uacc[nf], 0, 0, 0);
      }
    }
#pragma unroll
    for (int nf = 0; nf < 4; ++nf) {
#pragma unroll
      for (int reg = 0; reg < 4; ++reg) {
        int m = lg4 * 4 + reg;
        int f = nf * 16 + lq;
        float gg = gacc[nf][reg];
        float uu = uacc[nf][reg];
        float sig = 1.f / (1.f + __expf(-gg));
        float av = gg * sig * uu * wts[reg];
        *(unsigned short*)((char*)&Act[wave][0] + ((m * 128 + f * 2) ^ ((m & 7) << 4))) = f2bh(av);
      }
    }
    bf16x8 afrag[2];
#pragma unroll
    for (int ks2 = 0; ks2 < 2; ++ks2)
      afrag[ks2] = *(const bf16x8*)((const char*)&Act[wave][0] + ((lq * 128 + ks2 * 64 + lg4 * 16) ^ ((lq & 7) << 4)));
#pragma unroll
    for (int nd = 0; nd < 8; ++nd) {
      int drow = nd * 16 + lq;
#pragma unroll
      for (int ks2 = 0; ks2 < 2; ++ks2) {
        bf16x8 b = *(const bf16x8*)((const char*)WstV + ((drow * 128 + ks2 * 64 + lg4 * 16) ^ ((drow & 7) << 4)));
        dacc[nd] = __builtin_amdgcn_mfma_f32_16x16x32_bf16(afrag[ks2], b, dacc[nd], 0, 0, 0);
      }
    }
  }
#pragma unroll
  for (int nd = 0; nd < 8; ++nd) {
    int d = nd * 16 + lq;
#pragma unroll
    for (int reg = 0; reg < 4; ++reg) {
      int mloc = wave * 16 + lg4 * 4 + reg;
      if (mloc < nr) {
        atomicAdd(&out[(size_t)sidx[mloc] * 2048 + n * 128 + d], dacc[nd][reg]);
      }
    }
  }
}

extern "C" void kernel_launch(void* const* d_in, const int* in_sizes, int n_in,
                              void* d_out, int out_size, void* d_ws, size_t ws_size,
                              hipStream_t stream) {
  const float* hidden = (const float*)d_in[0];
  const float* cosb   = (const float*)d_in[1];
  const float* sinb   = (const float*)d_in[2];
  // d_in[3] = attn_mask (unused; causal handled analytically)
  const float* ln1w   = (const float*)d_in[4];
  const float* ln2w   = (const float*)d_in[5];
  const float* wq     = (const float*)d_in[6];
  const float* wk     = (const float*)d_in[7];
  const float* wv     = (const float*)d_in[8];
  const float* wo     = (const float*)d_in[9];
  const float* mhw    = (const float*)d_in[10];
  const float* rw     = (const float*)d_in[11];
  const float* kww    = (const float*)d_in[12];
  const float* uww    = (const float*)d_in[13];
  const float* vww    = (const float*)d_in[14];
  float* out = (float*)d_out;

  float* ws = (float*)d_ws;
  float* qb    = ws;                        // 1024x2048 f32
  float* kb    = qb + 2097152;              // 1024x512 f32
  float* yb    = kb + 524288;               // 1024x2048 f32
  int*   cntb  = (int*)(yb + 2097152);      // 128
  int*   idxb  = cntb + 128;                // 128K
  float* wtb   = (float*)(idxb + 131072);   // 128K
  unsigned short* xb    = (unsigned short*)(wtb + 131072);  // 1024x2048 bf16
  unsigned short* qbb   = xb + 2097152;     // 1024x2048
  unsigned short* kbb   = qbb + 2097152;    // 1024x512
  unsigned short* vbb   = kbb + 524288;     // 1024x512
  unsigned short* attnbb= vbb + 524288;     // 1024x2048
  unsigned short* ybb   = attnbb + 2097152; // 1024x2048
  unsigned short* kwb   = ybb + 2097152;    // 32x256x128
  unsigned short* uwb   = kwb + 1048576;
  unsigned short* vwtb  = uwb + 1048576;    // 32x128x256 (transposed)

  hipMemsetAsync(cntb, 0, 128 * sizeof(int), stream);

  convert_kuw_kernel<<<dim3(512, 2), 256, 0, stream>>>(kww, uww, kwb, uwb);
  transpose_vw_kernel<<<dim3(32, 4, 2), 256, 0, stream>>>(vww, vwtb);

  rmsnorm1_kernel<<<S_, 256, 0, stream>>>(hidden, ln1w, xb);

  qkv_mfma_kernel<<<384, 256, 0, stream>>>(xb, wq, wk, wv, qb, kb, vbb);

  rope_kernel<<<S_, 256, 0, stream>>>(qb, kb, cosb, sinb, qbb, kbb);

  attn_mfma_kernel<<<dim3(NH_, S_ / 64), 256, 0, stream>>>(qbb, kbb, vbb, attnbb);

  wo_mfma_kernel<<<256, 256, 0, stream>>>(attnbb, wo, hidden, out);

  rmsnorm2_kernel<<<S_, 256, 0, stream>>>(out, ln2w, mhw, yb, ybb);

  route_kernel<<<S_, 128, 0, stream>>>(yb, rw, cntb, idxb, wtb);

  moe_ffn_mfma_kernel<<<dim3(128, 16), 256, 0, stream>>>(ybb, kwb, uwb, vwtb, cntb, idxb, wtb, out);
}

// Round 7
// 357.133 us; speedup vs baseline: 7.0622x; 1.0592x over previous
//
#include <hip/hip_runtime.h>
#include <hip/hip_bf16.h>

#define S_ 1024
#define H_ 2048
#define NH_ 16
#define NKV_ 4
#define HD_ 128
#define E_ 8
#define F_ 256
#define EPS_ 1e-6f
#define SCALE_ 0.08838834764831845f  // 128^-0.5

typedef __attribute__((ext_vector_type(8))) short bf16x8;
typedef __attribute__((ext_vector_type(4))) float f32x4;

static __device__ __forceinline__ unsigned short f2bf(float x) {
  unsigned u = __float_as_uint(x);
  unsigned r = (u + 0x7FFFu + ((u >> 16) & 1u)) >> 16;
  return (unsigned short)r;
}
static __device__ __forceinline__ unsigned short f2bh(float x) {
  __hip_bfloat16 b = __float2bfloat16(x);
  return *reinterpret_cast<unsigned short*>(&b);
}

// ---------------- RMSNorm #1 -> bf16 ----------------
__global__ void rmsnorm1_kernel(const float* __restrict__ in, const float* __restrict__ w,
                                unsigned short* __restrict__ outb) {
  int s = blockIdx.x, tid = threadIdx.x;
  const float* row = in + s * H_;
  __shared__ float red[256];
  float ss = 0.f;
  for (int i = tid; i < H_; i += 256) { float v = row[i]; ss += v * v; }
  red[tid] = ss; __syncthreads();
  for (int off = 128; off > 0; off >>= 1) {
    if (tid < off) red[tid] += red[tid + off];
    __syncthreads();
  }
  float rs = rsqrtf(red[0] / H_ + EPS_);
  for (int i = tid; i < H_; i += 256) outb[(size_t)s * H_ + i] = f2bh(row[i] * rs * w[i]);
}

// ---------------- weight prep: kw/uw fp32 -> bf16 ----------------
__global__ __launch_bounds__(256) void convert_kuw_kernel(const float* __restrict__ kw,
                                                          const float* __restrict__ uw,
                                                          unsigned short* __restrict__ kwb,
                                                          unsigned short* __restrict__ uwb) {
  const float* src = (blockIdx.y == 0) ? kw : uw;
  unsigned short* dst = (blockIdx.y == 0) ? kwb : uwb;
  size_t i = ((size_t)blockIdx.x * 256 + threadIdx.x) * 8;
  float4 a = *(const float4*)&src[i];
  float4 b = *(const float4*)&src[i + 4];
  ushort4 ua, ub;
  ua.x = f2bh(a.x); ua.y = f2bh(a.y); ua.z = f2bh(a.z); ua.w = f2bh(a.w);
  ub.x = f2bh(b.x); ub.y = f2bh(b.y); ub.z = f2bh(b.z); ub.w = f2bh(b.w);
  *(ushort4*)&dst[i] = ua;
  *(ushort4*)&dst[i + 4] = ub;
}

// ---------------- weight prep: vw [e][256 f][128 d] -> vwtb bf16 [e][128 d][256 f]
__global__ __launch_bounds__(256) void transpose_vw_kernel(const float* __restrict__ vw,
                                                           unsigned short* __restrict__ vwtb) {
  int e = blockIdx.x, ft = blockIdx.y, dt = blockIdx.z;  // (32, 4, 2)
  int tid = threadIdx.x;
  __shared__ float tile[64][65];
  const float* src = vw + ((size_t)e * 256 + ft * 64) * 128 + dt * 64;
#pragma unroll
  for (int it = 0; it < 4; ++it) {
    int idx = it * 256 + tid;
    int r = idx >> 4, c4 = (idx & 15) * 4;
    float4 v = *(const float4*)&src[(size_t)r * 128 + c4];
    tile[r][c4] = v.x; tile[r][c4 + 1] = v.y; tile[r][c4 + 2] = v.z; tile[r][c4 + 3] = v.w;
  }
  __syncthreads();
  unsigned short* dst = vwtb + ((size_t)e * 128 + dt * 64) * 256 + ft * 64;
#pragma unroll
  for (int it = 0; it < 4; ++it) {
    int idx = it * 256 + tid;
    int dl = idx >> 4, f4 = (idx & 15) * 4;
    ushort4 u;
    u.x = f2bh(tile[f4 + 0][dl]); u.y = f2bh(tile[f4 + 1][dl]);
    u.z = f2bh(tile[f4 + 2][dl]); u.w = f2bh(tile[f4 + 3][dl]);
    *(ushort4*)&dst[(size_t)dl * 256 + f4] = u;
  }
}

// ---------------- V transpose: vbb [s][g*128+d] -> vtb [g*128+d][s] (bf16) ----
__global__ __launch_bounds__(256) void transpose_v_kernel(const unsigned short* __restrict__ vbb,
                                                          unsigned short* __restrict__ vtb) {
  int g = blockIdx.x, st = blockIdx.y, dt = blockIdx.z;  // (4, 16, 2)
  int tid = threadIdx.x;
  __shared__ unsigned short tile[64][65];
  int s0 = st * 64, d0 = dt * 64;
#pragma unroll
  for (int it = 0; it < 16; ++it) {
    int idx = it * 256 + tid;
    int r = idx >> 6, c = idx & 63;
    tile[r][c] = vbb[(size_t)(s0 + r) * 512 + g * 128 + d0 + c];
  }
  __syncthreads();
#pragma unroll
  for (int it = 0; it < 16; ++it) {
    int idx = it * 256 + tid;
    int dl = idx >> 6, c = idx & 63;
    vtb[(size_t)(g * 128 + d0 + dl) * 1024 + s0 + c] = tile[c][dl];
  }
}

// ============ pipelined bf16 MFMA GEMM (64x128 tile, BK=64, dbuf LDS) ============
// ---- fused QKV
__global__ __launch_bounds__(256) void qkv_mfma_kernel(const unsigned short* __restrict__ xb,
                                                       const float* __restrict__ wq,
                                                       const float* __restrict__ wk,
                                                       const float* __restrict__ wv,
                                                       float* __restrict__ qb,
                                                       float* __restrict__ kb,
                                                       unsigned short* __restrict__ vbb) {
  int bid = blockIdx.x;                       // 384
  int swz = (bid & 7) * 48 + (bid >> 3);      // bijective (384 % 8 == 0)
  int bm = (swz / 24) * 64;
  int bn = (swz % 24) * 128;
  const float* B; float* C = nullptr; unsigned short* Cb = nullptr; int ldc, cb;
  if (bn < 2048)      { B = wq + (size_t)bn * 2048;          C = qb; ldc = 2048; cb = bn; }
  else if (bn < 2560) { B = wk + (size_t)(bn - 2048) * 2048; C = kb; ldc = 512;  cb = bn - 2048; }
  else                { B = wv + (size_t)(bn - 2560) * 2048; Cb = vbb; ldc = 512; cb = bn - 2560; }
  int tid = threadIdx.x, wave = tid >> 6, lane = tid & 63;
  int lq = lane & 15, lg4 = lane >> 4;
  int wr = (wave >> 1) * 32, wc = (wave & 1) * 64;
  __shared__ __align__(16) unsigned short Als[2][64 * 64];
  __shared__ __align__(16) unsigned short Bls[2][128 * 64];
  f32x4 acc[2][4];
#pragma unroll
  for (int i = 0; i < 2; ++i)
#pragma unroll
    for (int j = 0; j < 4; ++j) acc[i][j] = (f32x4){0.f, 0.f, 0.f, 0.f};

  int ar = (tid >> 3), ac8 = (tid & 7) * 8;
  int br = (tid >> 4), bc4 = (tid & 15) * 4;
  bf16x8 areg[2];
  float4 breg[8];

  auto LOAD = [&](int k0) {
#pragma unroll
    for (int it = 0; it < 2; ++it)
      areg[it] = *(const bf16x8*)&xb[(size_t)(bm + ar + it * 32) * 2048 + k0 + ac8];
#pragma unroll
    for (int it = 0; it < 8; ++it)
      breg[it] = *(const float4*)&B[(size_t)(br + it * 16) * 2048 + k0 + bc4];
  };
  auto STORE = [&](int buf) {
#pragma unroll
    for (int it = 0; it < 2; ++it) {
      int r = ar + it * 32;
      *(bf16x8*)((char*)&Als[buf][0] + ((r * 128 + ac8 * 2) ^ ((r & 7) << 4))) = areg[it];
    }
#pragma unroll
    for (int it = 0; it < 8; ++it) {
      int r = br + it * 16;
      ushort4 u;
      u.x = f2bh(breg[it].x); u.y = f2bh(breg[it].y);
      u.z = f2bh(breg[it].z); u.w = f2bh(breg[it].w);
      *(ushort4*)((char*)&Bls[buf][0] + ((r * 128 + bc4 * 2) ^ ((r & 7) << 4))) = u;
    }
  };

  LOAD(0); STORE(0); __syncthreads();
  int cur = 0;
  for (int t = 0; t < 32; ++t) {
    if (t < 31) LOAD((t + 1) * 64);
#pragma unroll
    for (int ks = 0; ks < 2; ++ks) {
      bf16x8 af[2], bfr[4];
#pragma unroll
      for (int mi = 0; mi < 2; ++mi) {
        int row = wr + mi * 16 + lq;
        af[mi] = *(const bf16x8*)((const char*)&Als[cur][0] + ((row * 128 + ks * 64 + lg4 * 16) ^ ((row & 7) << 4)));
      }
#pragma unroll
      for (int ni = 0; ni < 4; ++ni) {
        int row = wc + ni * 16 + lq;
        bfr[ni] = *(const bf16x8*)((const char*)&Bls[cur][0] + ((row * 128 + ks * 64 + lg4 * 16) ^ ((row & 7) << 4)));
      }
#pragma unroll
      for (int mi = 0; mi < 2; ++mi)
#pragma unroll
        for (int ni = 0; ni < 4; ++ni)
          acc[mi][ni] = __builtin_amdgcn_mfma_f32_16x16x32_bf16(af[mi], bfr[ni], acc[mi][ni], 0, 0, 0);
    }
    if (t < 31) STORE(cur ^ 1);
    __syncthreads();
    cur ^= 1;
  }
#pragma unroll
  for (int mi = 0; mi < 2; ++mi)
#pragma unroll
    for (int ni = 0; ni < 4; ++ni) {
      int col = cb + wc + ni * 16 + lq;
#pragma unroll
      for (int reg = 0; reg < 4; ++reg) {
        int m = bm + wr + mi * 16 + lg4 * 4 + reg;
        if (C) C[(size_t)m * ldc + col] = acc[mi][ni][reg];
        else   Cb[(size_t)m * ldc + col] = f2bh(acc[mi][ni][reg]);
      }
    }
}

// ---- WO GEMM with residual: out = attnbb(bf16) @ wo(f32)^T + hidden
__global__ __launch_bounds__(256) void wo_mfma_kernel(const unsigned short* __restrict__ A,
                                                      const float* __restrict__ Bmat,
                                                      const float* __restrict__ resid,
                                                      float* __restrict__ C) {
  int bid = blockIdx.x;                       // 256
  int swz = (bid & 7) * 32 + (bid >> 3);
  int bm = (swz / 16) * 64;
  int bn = (swz % 16) * 128;
  int tid = threadIdx.x, wave = tid >> 6, lane = tid & 63;
  int lq = lane & 15, lg4 = lane >> 4;
  int wr = (wave >> 1) * 32, wc = (wave & 1) * 64;
  __shared__ __align__(16) unsigned short Als[2][64 * 64];
  __shared__ __align__(16) unsigned short Bls[2][128 * 64];
  f32x4 acc[2][4];
#pragma unroll
  for (int i = 0; i < 2; ++i)
#pragma unroll
    for (int j = 0; j < 4; ++j) acc[i][j] = (f32x4){0.f, 0.f, 0.f, 0.f};

  int ar = (tid >> 3), ac8 = (tid & 7) * 8;
  int br = (tid >> 4), bc4 = (tid & 15) * 4;
  bf16x8 areg[2];
  float4 breg[8];

  auto LOAD = [&](int k0) {
#pragma unroll
    for (int it = 0; it < 2; ++it)
      areg[it] = *(const bf16x8*)&A[(size_t)(bm + ar + it * 32) * 2048 + k0 + ac8];
#pragma unroll
    for (int it = 0; it < 8; ++it)
      breg[it] = *(const float4*)&Bmat[(size_t)(bn + br + it * 16) * 2048 + k0 + bc4];
  };
  auto STORE = [&](int buf) {
#pragma unroll
    for (int it = 0; it < 2; ++it) {
      int r = ar + it * 32;
      *(bf16x8*)((char*)&Als[buf][0] + ((r * 128 + ac8 * 2) ^ ((r & 7) << 4))) = areg[it];
    }
#pragma unroll
    for (int it = 0; it < 8; ++it) {
      int r = br + it * 16;
      ushort4 u;
      u.x = f2bh(breg[it].x); u.y = f2bh(breg[it].y);
      u.z = f2bh(breg[it].z); u.w = f2bh(breg[it].w);
      *(ushort4*)((char*)&Bls[buf][0] + ((r * 128 + bc4 * 2) ^ ((r & 7) << 4))) = u;
    }
  };

  LOAD(0); STORE(0); __syncthreads();
  int cur = 0;
  for (int t = 0; t < 32; ++t) {
    if (t < 31) LOAD((t + 1) * 64);
#pragma unroll
    for (int ks = 0; ks < 2; ++ks) {
      bf16x8 af[2], bfr[4];
#pragma unroll
      for (int mi = 0; mi < 2; ++mi) {
        int row = wr + mi * 16 + lq;
        af[mi] = *(const bf16x8*)((const char*)&Als[cur][0] + ((row * 128 + ks * 64 + lg4 * 16) ^ ((row & 7) << 4)));
      }
#pragma unroll
      for (int ni = 0; ni < 4; ++ni) {
        int row = wc + ni * 16 + lq;
        bfr[ni] = *(const bf16x8*)((const char*)&Bls[cur][0] + ((row * 128 + ks * 64 + lg4 * 16) ^ ((row & 7) << 4)));
      }
#pragma unroll
      for (int mi = 0; mi < 2; ++mi)
#pragma unroll
        for (int ni = 0; ni < 4; ++ni)
          acc[mi][ni] = __builtin_amdgcn_mfma_f32_16x16x32_bf16(af[mi], bfr[ni], acc[mi][ni], 0, 0, 0);
    }
    if (t < 31) STORE(cur ^ 1);
    __syncthreads();
    cur ^= 1;
  }
#pragma unroll
  for (int mi = 0; mi < 2; ++mi)
#pragma unroll
    for (int ni = 0; ni < 4; ++ni) {
      int col = bn + wc + ni * 16 + lq;
#pragma unroll
      for (int reg = 0; reg < 4; ++reg) {
        int m = bm + wr + mi * 16 + lg4 * 4 + reg;
        C[(size_t)m * 2048 + col] = acc[mi][ni][reg] + resid[(size_t)m * 2048 + col];
      }
    }
}

// ---------------- RoPE: fp32 q/k -> rotated bf16 copies ----------------
__global__ void rope_kernel(const float* __restrict__ qb, const float* __restrict__ kb,
                            const float* __restrict__ cosb, const float* __restrict__ sinb,
                            unsigned short* __restrict__ qbb, unsigned short* __restrict__ kbb) {
  int s = blockIdx.x, tid = threadIdx.x;
  for (int idx = tid; idx < (NH_ + NKV_) * 64; idx += 256) {
    int hh = idx >> 6;
    int d = idx & 63;
    float c0 = cosb[s * HD_ + d], s0 = sinb[s * HD_ + d];
    float c1 = cosb[s * HD_ + d + 64], s1 = sinb[s * HD_ + d + 64];
    const float* src; unsigned short* dst;
    if (hh < NH_) { src = qb + (size_t)s * 2048 + hh * 128; dst = qbb + (size_t)s * 2048 + hh * 128; }
    else          { src = kb + (size_t)s * 512 + (hh - NH_) * 128; dst = kbb + (size_t)s * 512 + (hh - NH_) * 128; }
    float a = src[d], b = src[d + 64];
    dst[d] = f2bh(a * c0 - b * s0);
    dst[d + 64] = f2bh(b * c1 + a * s1);
  }
}

// ---------------- MFMA flash attention (causal GQA), dbuf + pre-transposed V ---
__global__ __launch_bounds__(256) void attn_mfma_kernel(const unsigned short* __restrict__ qbb,
                                                        const unsigned short* __restrict__ kbb,
                                                        const unsigned short* __restrict__ vtb,
                                                        unsigned short* __restrict__ ob) {
  int n = blockIdx.x, qt = blockIdx.y;
  int g = n >> 2;
  int tid = threadIdx.x;
  int wave = tid >> 6, lane = tid & 63;
  int lq = lane & 15, lg4 = lane >> 4;

  __shared__ __align__(16) unsigned short Kls[2][64 * 128];
  __shared__ __align__(16) unsigned short Vls[2][128 * 64];
  __shared__ __align__(16) unsigned short Pls[4][16 * 64];
  __shared__ __align__(16) float corr_ls[4][16];
  __shared__ __align__(16) float lsum_ls[4][16];

  int q0 = qt * 64 + wave * 16;
  bf16x8 qfrag[4];
  {
    const unsigned short* qp = qbb + (size_t)(q0 + lq) * 2048 + n * 128;
#pragma unroll
    for (int ks = 0; ks < 4; ++ks)
      qfrag[ks] = *(const bf16x8*)&qp[ks * 32 + lg4 * 8];
  }
  f32x4 oacc[8];
#pragma unroll
  for (int i = 0; i < 8; ++i) oacc[i] = (f32x4){0.f, 0.f, 0.f, 0.f};
  float mrow = -1e30f, lrow = 0.f;

  // staging indices: K rows kr+it*16 (cols kc8), V^T rows vr+it*32 (cols vc8)
  int kr = tid >> 4, kc8 = (tid & 15) * 8;
  int vr = tid >> 3, vc8 = (tid & 7) * 8;
  bf16x8 kreg[4], vreg[4];

  auto LOADKV = [&](int t) {
    int kv0 = t * 64;
#pragma unroll
    for (int it = 0; it < 4; ++it)
      kreg[it] = *(const bf16x8*)&kbb[(size_t)(kv0 + kr + it * 16) * 512 + g * 128 + kc8];
#pragma unroll
    for (int it = 0; it < 4; ++it)
      vreg[it] = *(const bf16x8*)&vtb[(size_t)(g * 128 + vr + it * 32) * 1024 + kv0 + vc8];
  };
  auto STOREKV = [&](int buf) {
#pragma unroll
    for (int it = 0; it < 4; ++it) {
      int r = kr + it * 16;
      *(bf16x8*)((char*)&Kls[buf][0] + ((r * 256 + kc8 * 2) ^ ((r & 7) << 4))) = kreg[it];
    }
#pragma unroll
    for (int it = 0; it < 4; ++it) {
      int r = vr + it * 32;
      *(bf16x8*)((char*)&Vls[buf][0] + ((r * 128 + vc8 * 2) ^ ((r & 7) << 4))) = vreg[it];
    }
  };

  int nt = qt + 1;
  LOADKV(0); STOREKV(0); __syncthreads();
  int cur = 0;
  for (int t = 0; t < nt; ++t) {
    int kv0 = t * 64;
    if (t + 1 < nt) LOADKV(t + 1);
    // ---- QK^T (scores^T): rows = k, cols = q
    f32x4 sacc[4];
#pragma unroll
    for (int i = 0; i < 4; ++i) sacc[i] = (f32x4){0.f, 0.f, 0.f, 0.f};
#pragma unroll
    for (int kt = 0; kt < 4; ++kt) {
      int row = kt * 16 + lq;
#pragma unroll
      for (int ks = 0; ks < 4; ++ks) {
        bf16x8 kf = *(const bf16x8*)((const char*)&Kls[cur][0] +
                     ((row * 256 + ks * 64 + lg4 * 16) ^ ((row & 7) << 4)));
        sacc[kt] = __builtin_amdgcn_mfma_f32_16x16x32_bf16(kf, qfrag[ks], sacc[kt], 0, 0, 0);
      }
    }
    int qg = q0 + lq;
    float s[16], p[16];
    float rmax = -1e30f;
#pragma unroll
    for (int kt = 0; kt < 4; ++kt) {
#pragma unroll
      for (int r = 0; r < 4; ++r) {
        int kg = kv0 + kt * 16 + lg4 * 4 + r;
        float v = sacc[kt][r] * SCALE_;
        v = (kg <= qg) ? v : -1e30f;
        s[kt * 4 + r] = v;
        rmax = fmaxf(rmax, v);
      }
    }
    rmax = fmaxf(rmax, __shfl_xor(rmax, 16));
    rmax = fmaxf(rmax, __shfl_xor(rmax, 32));
    float mnew = fmaxf(mrow, rmax);
    float corr = __expf(mrow - mnew);
    float psum = 0.f;
#pragma unroll
    for (int i = 0; i < 16; ++i) { p[i] = __expf(s[i] - mnew); psum += p[i]; }
    psum += __shfl_xor(psum, 16);
    psum += __shfl_xor(psum, 32);
    lrow = lrow * corr + psum;
    mrow = mnew;
    if (lane < 16) corr_ls[wave][lq] = corr;
#pragma unroll
    for (int kt = 0; kt < 4; ++kt) {
      unsigned u0 = (unsigned)f2bf(p[kt * 4 + 0]) | ((unsigned)f2bf(p[kt * 4 + 1]) << 16);
      unsigned u1 = (unsigned)f2bf(p[kt * 4 + 2]) | ((unsigned)f2bf(p[kt * 4 + 3]) << 16);
      int colb = kt * 32 + lg4 * 8;
      *(unsigned*)((char*)&Pls[wave][0] + ((lq * 128 + colb) ^ ((lq & 7) << 4))) = u0;
      *(unsigned*)((char*)&Pls[wave][0] + ((lq * 128 + colb + 4) ^ ((lq & 7) << 4))) = u1;
    }
    f32x4 c4v = *(const f32x4*)&corr_ls[wave][lg4 * 4];
#pragma unroll
    for (int dt = 0; dt < 8; ++dt) {
#pragma unroll
      for (int r = 0; r < 4; ++r) oacc[dt][r] *= c4v[r];
    }
    bf16x8 pfrag[2];
#pragma unroll
    for (int ks2 = 0; ks2 < 2; ++ks2)
      pfrag[ks2] = *(const bf16x8*)((const char*)&Pls[wave][0] +
                    ((lq * 128 + ks2 * 64 + lg4 * 16) ^ ((lq & 7) << 4)));
#pragma unroll
    for (int dt = 0; dt < 8; ++dt) {
      int dr = dt * 16 + lq;
#pragma unroll
      for (int ks2 = 0; ks2 < 2; ++ks2) {
        bf16x8 vf = *(const bf16x8*)((const char*)&Vls[cur][0] +
                     ((dr * 128 + ks2 * 64 + lg4 * 16) ^ ((dr & 7) << 4)));
        oacc[dt] = __builtin_amdgcn_mfma_f32_16x16x32_bf16(pfrag[ks2], vf, oacc[dt], 0, 0, 0);
      }
    }
    if (t + 1 < nt) STOREKV(cur ^ 1);
    __syncthreads();
    cur ^= 1;
  }
  if (lane < 16) lsum_ls[wave][lq] = lrow;
  f32x4 l4 = *(const f32x4*)&lsum_ls[wave][lg4 * 4];
#pragma unroll
  for (int dt = 0; dt < 8; ++dt) {
#pragma unroll
    for (int r = 0; r < 4; ++r) {
      ob[(size_t)(q0 + lg4 * 4 + r) * 2048 + n * 128 + dt * 16 + lq] = f2bh(oacc[dt][r] / l4[r]);
    }
  }
}

// ---------------- RMSNorm #2 (row norm, per-head norm; fp32 + bf16 outputs) ---
__global__ void rmsnorm2_kernel(const float* __restrict__ hin, const float* __restrict__ ln2w,
                                const float* __restrict__ mhw, float* __restrict__ yout,
                                unsigned short* __restrict__ ybb) {
  int s = blockIdx.x, tid = threadIdx.x;  // 256
  const float* row = hin + (size_t)s * H_;
  __shared__ float y1[H_];
  __shared__ float red[256];
  __shared__ float ph[16][17];
  float ss = 0.f;
  for (int i = tid; i < H_; i += 256) { float v = row[i]; ss += v * v; }
  red[tid] = ss; __syncthreads();
  for (int off = 128; off > 0; off >>= 1) {
    if (tid < off) red[tid] += red[tid + off];
    __syncthreads();
  }
  float rs1 = rsqrtf(red[0] / H_ + EPS_);
  for (int i = tid; i < H_; i += 256) y1[i] = row[i] * rs1 * ln2w[i];
  __syncthreads();
  int n = tid >> 4, j = tid & 15;
  float s2 = 0.f;
  for (int d = j * 8; d < j * 8 + 8; ++d) { float v = y1[n * 128 + d]; s2 += v * v; }
  ph[n][j] = s2; __syncthreads();
  if (j == 0) {
    float t = 0.f;
    for (int q = 0; q < 16; ++q) t += ph[n][q];
    ph[n][16] = rsqrtf(t / HD_ + EPS_);
  }
  __syncthreads();
  for (int i = tid; i < H_; i += 256) {
    int hn = i >> 7;
    float v = y1[i] * ph[hn][16] * mhw[i];
    yout[(size_t)s * H_ + i] = v;
    ybb[(size_t)s * H_ + i] = f2bh(v);
  }
}

// ---------------- router: softmax + top2 + scatter into expert lists ---------
__global__ void route_kernel(const float* __restrict__ yb, const float* __restrict__ rw,
                             int* __restrict__ cnt, int* __restrict__ idxb,
                             float* __restrict__ wtb) {
  int s = blockIdx.x, tid = threadIdx.x;  // 128
  int n = tid >> 3, e = tid & 7;
  const float* yrow = yb + (size_t)s * 2048 + n * 128;
  const float* wrow = rw + (size_t)(n * 8 + e) * 128;
  float lg = 0.f;
  for (int d = 0; d < 128; ++d) lg += yrow[d] * wrow[d];
  float mx = lg;
  for (int off = 1; off < 8; off <<= 1) mx = fmaxf(mx, __shfl_xor(mx, off));
  float p = __expf(lg - mx);
  float sum = p;
  for (int off = 1; off < 8; off <<= 1) sum += __shfl_xor(sum, off);
  float rp = p / sum;
  float v1 = rp; int i1 = e;
  for (int off = 1; off < 8; off <<= 1) {
    float ov = __shfl_xor(v1, off); int oi = __shfl_xor(i1, off);
    if (ov > v1 || (ov == v1 && oi < i1)) { v1 = ov; i1 = oi; }
  }
  float v2 = (e == i1) ? -1e30f : rp; int i2 = e;
  for (int off = 1; off < 8; off <<= 1) {
    float ov = __shfl_xor(v2, off); int oi = __shfl_xor(i2, off);
    if (ov > v2 || (ov == v2 && oi < i2)) { v2 = ov; i2 = oi; }
  }
  if (e == 0) {
    float wsum = v1 + v2;
    int pe1 = n * 8 + i1;
    int pos1 = atomicAdd(&cnt[pe1], 1);
    idxb[pe1 * S_ + pos1] = s; wtb[pe1 * S_ + pos1] = v1 / wsum;
    int pe2 = n * 8 + i2;
    int pos2 = atomicAdd(&cnt[pe2], 1);
    idxb[pe2 * S_ + pos2] = s; wtb[pe2 * S_ + pos2] = v2 / wsum;
  }
}

// ---------------- MoE FFN: bf16 weights, fused per-fc pipeline ------------
__global__ __launch_bounds__(256) void moe_ffn_mfma_kernel(
    const unsigned short* __restrict__ ybb, const unsigned short* __restrict__ kwb,
    const unsigned short* __restrict__ uwb, const unsigned short* __restrict__ vwtb,
    const int* __restrict__ cnt, const int* __restrict__ idxb,
    const float* __restrict__ wtb, float* __restrict__ out) {
  int pe = blockIdx.x;
  int c = cnt[pe];
  int base = blockIdx.y * 64;
  if (base >= c) return;
  int n = pe >> 3, e = pe & 7, g = n >> 2;
  int eW = g * 8 + e;
  int nr = min(64, c - base);
  int tid = threadIdx.x, wave = tid >> 6, lane = tid & 63;
  int lq = lane & 15, lg4 = lane >> 4;

  __shared__ __align__(16) unsigned short Yls[64 * 128];
  __shared__ __align__(16) unsigned short WstK[64 * 128];
  __shared__ __align__(16) unsigned short WstU[64 * 128];
  __shared__ __align__(16) unsigned short WstV[128 * 64];
  __shared__ __align__(16) unsigned short Act[4][16 * 64];
  __shared__ int sidx[64];
  __shared__ float swt[64];

  if (tid < 64) {
    sidx[tid] = (tid < nr) ? idxb[pe * S_ + base + tid] : 0;
    swt[tid]  = (tid < nr) ? wtb[pe * S_ + base + tid] : 0.f;
  }
  __syncthreads();
#pragma unroll
  for (int it = 0; it < 4; ++it) {
    int idx = it * 256 + tid;
    int r = idx >> 4, c8 = (idx & 15) * 8;
    bf16x8 v = {0, 0, 0, 0, 0, 0, 0, 0};
    if (r < nr) v = *(const bf16x8*)&ybb[(size_t)sidx[r] * 2048 + n * 128 + c8];
    *(bf16x8*)((char*)Yls + ((r * 256 + c8 * 2) ^ ((r & 7) << 4))) = v;
  }
  __syncthreads();
  bf16x8 yfrag[4];
  {
    int arow = wave * 16 + lq;
#pragma unroll
    for (int ks = 0; ks < 4; ++ks)
      yfrag[ks] = *(const bf16x8*)((const char*)Yls + ((arow * 256 + ks * 64 + lg4 * 16) ^ ((arow & 7) << 4)));
  }
  float wts[4];
#pragma unroll
  for (int reg = 0; reg < 4; ++reg) wts[reg] = swt[wave * 16 + lg4 * 4 + reg];

  f32x4 dacc[8];
#pragma unroll
  for (int i = 0; i < 8; ++i) dacc[i] = (f32x4){0.f, 0.f, 0.f, 0.f};

  for (int fc = 0; fc < 4; ++fc) {
    __syncthreads();
#pragma unroll
    for (int it = 0; it < 4; ++it) {
      int idx = it * 256 + tid;
      int r = idx >> 4, c8 = (idx & 15) * 8;
      size_t goff = ((size_t)(eW * 256 + fc * 64 + r)) * 128 + c8;
      bf16x8 kv = *(const bf16x8*)&kwb[goff];
      *(bf16x8*)((char*)WstK + ((r * 256 + c8 * 2) ^ ((r & 7) << 4))) = kv;
      bf16x8 uv = *(const bf16x8*)&uwb[goff];
      *(bf16x8*)((char*)WstU + ((r * 256 + c8 * 2) ^ ((r & 7) << 4))) = uv;
    }
#pragma unroll
    for (int it = 0; it < 4; ++it) {
      int idx = it * 256 + tid;
      int r = idx >> 3, c8 = (idx & 7) * 8;
      bf16x8 vv = *(const bf16x8*)&vwtb[((size_t)(eW * 128 + r)) * 256 + fc * 64 + c8];
      *(bf16x8*)((char*)WstV + ((r * 128 + c8 * 2) ^ ((r & 7) << 4))) = vv;
    }
    __syncthreads();
    f32x4 gacc[4], uacc[4];
#pragma unroll
    for (int i = 0; i < 4; ++i) { gacc[i] = (f32x4){0.f, 0.f, 0.f, 0.f}; uacc[i] = (f32x4){0.f, 0.f, 0.f, 0.f}; }
#pragma unroll
    for (int ks = 0; ks < 4; ++ks) {
#pragma unroll
      for (int nf = 0; nf < 4; ++nf) {
        int brow = nf * 16 + lq;
        bf16x8 bk = *(const bf16x8*)((const char*)WstK + ((brow * 256 + ks * 64 + lg4 * 16) ^ ((brow & 7) << 4)));
        gacc[nf] = __builtin_amdgcn_mfma_f32_16x16x32_bf16(yfrag[ks], bk, gacc[nf], 0, 0, 0);
        bf16x8 bu = *(const bf16x8*)((const char*)WstU + ((brow * 256 + ks * 64 + lg4 * 16) ^ ((brow & 7) << 4)));
        uacc[nf] = __builtin_amdgcn_mfma_f32_16x16x32_bf16(yfrag[ks], bu, uacc[nf], 0, 0, 0);
      }
    }
#pragma unroll
    for (int nf = 0; nf < 4; ++nf) {
#pragma unroll
      for (int reg = 0; reg < 4; ++reg) {
        int m = lg4 * 4 + reg;
        int f = nf * 16 + lq;
        float gg = gacc[nf][reg];
        float uu = uacc[nf][reg];
        float sig = 1.f / (1.f + __expf(-gg));
        float av = gg * sig * uu * wts[reg];
        *(unsigned short*)((char*)&Act[wave][0] + ((m * 128 + f * 2) ^ ((m & 7) << 4))) = f2bh(av);
      }
    }
    bf16x8 afrag[2];
#pragma unroll
    for (int ks2 = 0; ks2 < 2; ++ks2)
      afrag[ks2] = *(const bf16x8*)((const char*)&Act[wave][0] + ((lq * 128 + ks2 * 64 + lg4 * 16) ^ ((lq & 7) << 4)));
#pragma unroll
    for (int nd = 0; nd < 8; ++nd) {
      int drow = nd * 16 + lq;
#pragma unroll
      for (int ks2 = 0; ks2 < 2; ++ks2) {
        bf16x8 b = *(const bf16x8*)((const char*)WstV + ((drow * 128 + ks2 * 64 + lg4 * 16) ^ ((drow & 7) << 4)));
        dacc[nd] = __builtin_amdgcn_mfma_f32_16x16x32_bf16(afrag[ks2], b, dacc[nd], 0, 0, 0);
      }
    }
  }
#pragma unroll
  for (int nd = 0; nd < 8; ++nd) {
    int d = nd * 16 + lq;
#pragma unroll
    for (int reg = 0; reg < 4; ++reg) {
      int mloc = wave * 16 + lg4 * 4 + reg;
      if (mloc < nr) {
        atomicAdd(&out[(size_t)sidx[mloc] * 2048 + n * 128 + d], dacc[nd][reg]);
      }
    }
  }
}

extern "C" void kernel_launch(void* const* d_in, const int* in_sizes, int n_in,
                              void* d_out, int out_size, void* d_ws, size_t ws_size,
                              hipStream_t stream) {
  const float* hidden = (const float*)d_in[0];
  const float* cosb   = (const float*)d_in[1];
  const float* sinb   = (const float*)d_in[2];
  // d_in[3] = attn_mask (unused; causal handled analytically)
  const float* ln1w   = (const float*)d_in[4];
  const float* ln2w   = (const float*)d_in[5];
  const float* wq     = (const float*)d_in[6];
  const float* wk     = (const float*)d_in[7];
  const float* wv     = (const float*)d_in[8];
  const float* wo     = (const float*)d_in[9];
  const float* mhw    = (const float*)d_in[10];
  const float* rw     = (const float*)d_in[11];
  const float* kww    = (const float*)d_in[12];
  const float* uww    = (const float*)d_in[13];
  const float* vww    = (const float*)d_in[14];
  float* out = (float*)d_out;

  float* ws = (float*)d_ws;
  float* qb    = ws;                        // 1024x2048 f32
  float* kb    = qb + 2097152;              // 1024x512 f32
  float* yb    = kb + 524288;               // 1024x2048 f32
  int*   cntb  = (int*)(yb + 2097152);      // 128
  int*   idxb  = cntb + 128;                // 128K
  float* wtb   = (float*)(idxb + 131072);   // 128K
  unsigned short* xb    = (unsigned short*)(wtb + 131072);  // 1024x2048 bf16
  unsigned short* qbb   = xb + 2097152;     // 1024x2048
  unsigned short* kbb   = qbb + 2097152;    // 1024x512
  unsigned short* vbb   = kbb + 524288;     // 1024x512
  unsigned short* vtb   = vbb + 524288;     // 4x128x1024 (V transposed)
  unsigned short* attnbb= vtb + 524288;     // 1024x2048
  unsigned short* ybb   = attnbb + 2097152; // 1024x2048
  unsigned short* kwb   = ybb + 2097152;    // 32x256x128
  unsigned short* uwb   = kwb + 1048576;
  unsigned short* vwtb  = uwb + 1048576;    // 32x128x256 (transposed)

  hipMemsetAsync(cntb, 0, 128 * sizeof(int), stream);

  convert_kuw_kernel<<<dim3(512, 2), 256, 0, stream>>>(kww, uww, kwb, uwb);
  transpose_vw_kernel<<<dim3(32, 4, 2), 256, 0, stream>>>(vww, vwtb);

  rmsnorm1_kernel<<<S_, 256, 0, stream>>>(hidden, ln1w, xb);

  qkv_mfma_kernel<<<384, 256, 0, stream>>>(xb, wq, wk, wv, qb, kb, vbb);

  rope_kernel<<<S_, 256, 0, stream>>>(qb, kb, cosb, sinb, qbb, kbb);

  transpose_v_kernel<<<dim3(4, 16, 2), 256, 0, stream>>>(vbb, vtb);

  attn_mfma_kernel<<<dim3(NH_, S_ / 64), 256, 0, stream>>>(qbb, kbb, vtb, attnbb);

  wo_mfma_kernel<<<256, 256, 0, stream>>>(attnbb, wo, hidden, out);

  rmsnorm2_kernel<<<S_, 256, 0, stream>>>(out, ln2w, mhw, yb, ybb);

  route_kernel<<<S_, 128, 0, stream>>>(yb, rw, cntb, idxb, wtb);

  moe_ffn_mfma_kernel<<<dim3(128, 16), 256, 0, stream>>>(ybb, kwb, uwb, vwtb, cntb, idxb, wtb, out);
}